// Round 4
// baseline (2249.383 us; speedup 1.0000x reference)
//
#include <hip/hip_runtime.h>

#define M_DIM 16384
#define K_DIM 768
#define N_DIM 12288
#define TOPK  32
#define NCHUNK (N_DIM / 128)   // 96 col-chunks per row

typedef float f32x4 __attribute__((ext_vector_type(4)));
typedef short s16x8 __attribute__((ext_vector_type(8)));

__device__ __forceinline__ unsigned f2u(float f) {
  union { float f; unsigned u; } v; v.f = f; return v.u;
}
__device__ __forceinline__ float u2f(unsigned u) {
  union { unsigned u; float f; } v; v.u = u; return v.f;
}
__device__ __forceinline__ unsigned fkey(float f) {
  const unsigned u = f2u(f);
  return u ^ (unsigned)(((int)u >> 31) | 0x80000000);
}
__device__ __forceinline__ float kinv(unsigned k) {
  return u2f((k & 0x80000000u) ? (k ^ 0x80000000u) : ~k);
}
__device__ __forceinline__ unsigned short bf16_rne(float f) {
  unsigned u = f2u(f);
  return (unsigned short)((u + 0x7FFFu + ((u >> 16) & 1u)) >> 16);
}

// ---------------------------------------------------------------------------
// Prep (fused): dec_w transpose + bf16 hi/lo splits of x and enc_w.
// ---------------------------------------------------------------------------
__global__ __launch_bounds__(256) void TopKSparseAutoencoder_51917564674099_prep(
    const float* __restrict__ x, const float* __restrict__ w,
    const float* __restrict__ dw,
    unsigned short* __restrict__ xhi, unsigned short* __restrict__ xlo,
    unsigned short* __restrict__ whi, unsigned short* __restrict__ wlo,
    float* __restrict__ WT, int do_t, int do_s)
{
  __shared__ float tile[32][33];
  const int b = (int)blockIdx.x;
  const int t = (int)threadIdx.x;

  if (b < 9216) {
    if (!do_t) return;
    const int bx = b % (N_DIM / 32);
    const int by = b / (N_DIM / 32);
    const int tx = t & 31, ty = t >> 5;           // 32 x 8
#pragma unroll
    for (int j = 0; j < 32; j += 8)
      tile[ty + j][tx] = dw[(size_t)(by * 32 + ty + j) * N_DIM + bx * 32 + tx];
    __syncthreads();
#pragma unroll
    for (int j = 0; j < 32; j += 8)
      WT[(size_t)(bx * 32 + ty + j) * K_DIM + by * 32 + tx] = tile[tx][ty + j];
    return;
  }
  if (!do_s) return;

  const float* src; unsigned short* dh; unsigned short* dl; int i, stride, n4;
  if (b < 9216 + 1024) {
    src = x; dh = xhi; dl = xlo;
    i = (b - 9216) * 256 + t; stride = 1024 * 256; n4 = M_DIM * K_DIM / 4;
  } else {
    src = w; dh = whi; dl = wlo;
    i = (b - 10240) * 256 + t; stride = 512 * 256; n4 = N_DIM * K_DIM / 4;
  }
  for (; i < n4; i += stride) {
    const float4 v = ((const float4*)src)[i];
    ushort4 h, l;
    h.x = bf16_rne(v.x); h.y = bf16_rne(v.y); h.z = bf16_rne(v.z); h.w = bf16_rne(v.w);
    l.x = bf16_rne(v.x - u2f((unsigned)h.x << 16));
    l.y = bf16_rne(v.y - u2f((unsigned)h.y << 16));
    l.z = bf16_rne(v.z - u2f((unsigned)h.z << 16));
    l.w = bf16_rne(v.w - u2f((unsigned)h.w << 16));
    ((ushort4*)dh)[i] = h;
    ((ushort4*)dl)[i] = l;
  }
}

// ---------------------------------------------------------------------------
// Main GEMM: z = x @ enc_w^T + enc_b via bf16x3 MFMA (fp32-equivalent).
// NEW: double-buffered LDS with stage-next-BEFORE-compute, ONE barrier per
// K-step.  bf16x3 regime: ~450 cyc own-wave work between load-issue and the
// barrier drain -> most of the global_load_lds latency is hidden.
// ---------------------------------------------------------------------------
__device__ __forceinline__ void mfma16(f32x4& d, s16x8 a, s16x8 b) {
  asm("v_mfma_f32_16x16x32_bf16 %0, %1, %2, %0" : "+v"(d) : "v"(a), "v"(b));
}

#define GL16(g, l) __builtin_amdgcn_global_load_lds(                      \
    (const __attribute__((address_space(1))) void*)(g),                   \
    (__attribute__((address_space(3))) void*)(l), 16, 0, 0)

__global__ __launch_bounds__(256, 2) void TopKSparseAutoencoder_51917564674099_kernel(
    const unsigned short* __restrict__ Ahi, const unsigned short* __restrict__ Alo,
    const unsigned short* __restrict__ Bhi, const unsigned short* __restrict__ Blo,
    const float* __restrict__ bias, float* __restrict__ Z,
    float* __restrict__ cmax, int do_cmax)
{
  __shared__ unsigned short lds[2][4][128][32];   // 64 KB double-buffered
  __shared__ float cmx[128][2];                   // chunk-max combine

  const int t    = (int)threadIdx.x;
  const int wid  = t >> 6;
  const int lane = t & 63;

  const int bid  = (int)(blockIdx.y * gridDim.x + blockIdx.x);
  const int bswz = (bid & 7) * (12288 / 8) + (bid >> 3);
  const int n0   = (bswz % 96) * 128;
  const int m0   = (bswz / 96) * 128;

  const int rr  = lane >> 2;
  const int kq  = lane & 3;
  const int rt0 = wid * 32 + rr;
  const int rt1 = rt0 + 16;
  const int kc0 = (kq ^ ((rt0 >> 1) & 3)) * 8;
  const int kc1 = (kq ^ ((rt1 >> 1) & 3)) * 8;
  const size_t offA0 = (size_t)(m0 + rt0) * K_DIM + kc0;
  const size_t offA1 = (size_t)(m0 + rt1) * K_DIM + kc1;
  const size_t offB0 = (size_t)(n0 + rt0) * K_DIM + kc0;
  const size_t offB1 = (size_t)(n0 + rt1) * K_DIM + kc1;

  const int wm = (wid >> 1) * 64;
  const int wn = (wid & 1) * 64;
  const int lr = lane & 15;
  const int lc = lane >> 4;

  f32x4 acc[4][4];
#pragma unroll
  for (int i = 0; i < 4; ++i)
#pragma unroll
    for (int j = 0; j < 4; ++j) acc[i][j] = (f32x4){0.f, 0.f, 0.f, 0.f};

#define STAGE(B, KOFF) do {                                          \
    GL16(Ahi + offA0 + (KOFF), &lds[B][0][wid * 32][0]);             \
    GL16(Ahi + offA1 + (KOFF), &lds[B][0][wid * 32 + 16][0]);        \
    GL16(Alo + offA0 + (KOFF), &lds[B][1][wid * 32][0]);             \
    GL16(Alo + offA1 + (KOFF), &lds[B][1][wid * 32 + 16][0]);        \
    GL16(Bhi + offB0 + (KOFF), &lds[B][2][wid * 32][0]);             \
    GL16(Bhi + offB1 + (KOFF), &lds[B][2][wid * 32 + 16][0]);        \
    GL16(Blo + offB0 + (KOFF), &lds[B][3][wid * 32][0]);             \
    GL16(Blo + offB1 + (KOFF), &lds[B][3][wid * 32 + 16][0]);        \
  } while (0)

  STAGE(0, 0);
  __syncthreads();                       // drains vmcnt(0): buf0 ready

  int cur = 0;
  for (int k0 = 0; k0 < K_DIM; k0 += 32) {
    if (k0 + 32 < K_DIM) STAGE(cur ^ 1, k0 + 32);   // prefetch next tile

    s16x8 ah[4], al[4], bh[4], bl[4];
#pragma unroll
    for (int i = 0; i < 4; ++i) {
      const int r = wm + i * 16 + lr;
      const int p = (lc ^ ((r >> 1) & 3)) * 8;
      ah[i] = *(const s16x8*)&lds[cur][0][r][p];
      al[i] = *(const s16x8*)&lds[cur][1][r][p];
    }
#pragma unroll
    for (int j = 0; j < 4; ++j) {
      const int r = wn + j * 16 + lr;
      const int p = (lc ^ ((r >> 1) & 3)) * 8;
      bh[j] = *(const s16x8*)&lds[cur][2][r][p];
      bl[j] = *(const s16x8*)&lds[cur][3][r][p];
    }
#pragma unroll
    for (int i = 0; i < 4; ++i)
#pragma unroll
      for (int j = 0; j < 4; ++j) {
        mfma16(acc[i][j], ah[i], bh[j]);
        mfma16(acc[i][j], ah[i], bl[j]);
        mfma16(acc[i][j], al[i], bh[j]);
      }
    __syncthreads();   // next buf ready (vmcnt drain) + guards buffer reuse
    cur ^= 1;
  }
#undef STAGE

  asm volatile("s_nop 7\n\ts_nop 7" :::);

  float mx[4][4];
#pragma unroll
  for (int i = 0; i < 4; ++i)
#pragma unroll
    for (int q = 0; q < 4; ++q) mx[i][q] = -3.4e38f;

#pragma unroll
  for (int j = 0; j < 4; ++j) {
    const int col = n0 + wn + j * 16 + lr;
    const float bb = bias[col];
#pragma unroll
    for (int i = 0; i < 4; ++i) {
      const int r0 = m0 + wm + i * 16 + lc * 4;
#pragma unroll
      for (int q = 0; q < 4; ++q) {
        const float val = acc[i][j][q] + bb;
        Z[(size_t)(r0 + q) * N_DIM + col] = val;
        mx[i][q] = fmaxf(mx[i][q], val);
      }
    }
  }

  if (do_cmax) {
#pragma unroll
    for (int s = 1; s < 16; s <<= 1)
#pragma unroll
      for (int i = 0; i < 4; ++i)
#pragma unroll
        for (int q = 0; q < 4; ++q)
          mx[i][q] = fmaxf(mx[i][q], __shfl_xor(mx[i][q], s));
    if (lr == 0) {
#pragma unroll
      for (int i = 0; i < 4; ++i)
#pragma unroll
        for (int q = 0; q < 4; ++q)
          cmx[wm + i * 16 + lc * 4 + q][wid & 1] = mx[i][q];
    }
    __syncthreads();
    if (t < 128)
      cmax[(size_t)(m0 + t) * NCHUNK + (n0 >> 7)] = fmaxf(cmx[t][0], cmx[t][1]);
  }
}

// ---------------------------------------------------------------------------
// fp32 VALU GEMM fallback (workspace too small for MFMA path)
// ---------------------------------------------------------------------------
__global__ void enc_gemm_f32_fb(
    const float* A, const float* B, const float* bias, float* Z)
{
  __shared__ float As[32][132];
  __shared__ float Bs[32][132];

  const int tx = (int)threadIdx.x;
  const int ty = (int)threadIdx.y;
  const int t  = ty * 16 + tx;
  const int n0 = (int)blockIdx.x * 128;
  const int m0 = (int)blockIdx.y * 128;
  const int r = t >> 1;
  const int h = (t & 1) * 16;

  float c[8][8];
#pragma unroll
  for (int i = 0; i < 8; ++i)
#pragma unroll
    for (int j = 0; j < 8; ++j) c[i][j] = 0.0f;

  for (int k0 = 0; k0 < K_DIM; k0 += 32) {
    const float* pa = A + (size_t)(m0 + r) * K_DIM + k0 + h;
    const float* pb = B + (size_t)(n0 + r) * K_DIM + k0 + h;
    float fa[16], fb[16];
#pragma unroll
    for (int j = 0; j < 16; ++j) fa[j] = pa[j];
#pragma unroll
    for (int j = 0; j < 16; ++j) fb[j] = pb[j];
#pragma unroll
    for (int j = 0; j < 16; ++j) As[h + j][r] = fa[j];
#pragma unroll
    for (int j = 0; j < 16; ++j) Bs[h + j][r] = fb[j];
    __syncthreads();

    for (int kk = 0; kk < 32; ++kk) {
      float av[8], bv[8];
#pragma unroll
      for (int i = 0; i < 8; ++i) av[i] = As[kk][ty * 8 + i];
#pragma unroll
      for (int j = 0; j < 8; ++j) bv[j] = Bs[kk][tx * 8 + j];
#pragma unroll
      for (int i = 0; i < 8; ++i)
#pragma unroll
        for (int j = 0; j < 8; ++j) c[i][j] += av[i] * bv[j];
    }
    __syncthreads();
  }

#pragma unroll
  for (int j = 0; j < 8; ++j) {
    const int col = n0 + tx * 8 + j;
    const float bb = bias[col];
#pragma unroll
    for (int i = 0; i < 8; ++i)
      Z[(size_t)(m0 + ty * 8 + i) * N_DIM + col] = c[i][j] + bb;
  }
}

// ---------------------------------------------------------------------------
// Fast decode v2: never reads the full Z row.
// Wave 0 alone: B-search over 96 chunk maxes -> eligible chunks (cmax >= B,
// ~32-40 of 96) -> scan ONLY those chunks (16-20 KB vs 48 KB) -> exact
// 32-bit candidate select.  Waves 1-3 only zero-stream the output row.
// Correctness: z >= B implies chunk max >= B, so eligible chunks contain
// every candidate; candidate select is R3's proven-exact from-scratch
// search.  Fallback (cc > 512; Z untouched): full-row block-wide search.
// ---------------------------------------------------------------------------
__global__ __launch_bounds__(256) void TopKSparseAutoencoder_51917564674099_zdecode(
    float* Z, const float* __restrict__ CMAX, const float* __restrict__ WT,
    const float* __restrict__ db, float* __restrict__ XR)
{
  __shared__ unsigned candk[512];
  __shared__ int      candi[512];
  __shared__ int      s_elig[NCHUNK];
  __shared__ unsigned red[2][2][4];
  __shared__ int s_ne, s_cc, s_nnz;
  __shared__ int   s_col[TOPK];
  __shared__ float s_val[TOPK];

  const int row  = (int)blockIdx.x;
  const int t    = (int)threadIdx.x;
  const int lane = t & 63;
  const int wid  = t >> 6;

  if (t == 0) { s_ne = 0; s_cc = 0; s_nnz = 0; }
  if (t < TOPK) { s_col[t] = 0; s_val[t] = 0.0f; }

  const float4* zr = (const float4*)(Z + (size_t)row * N_DIM);

  // ================= phase 1: wave 0 does B, eligibility, scan ============
  if (wid == 0) {
    const unsigned kA = fkey(CMAX[(size_t)row * NCHUNK + lane]);
    const unsigned kB = (lane < NCHUNK - 64) ? fkey(CMAX[(size_t)row * NCHUNK + 64 + lane]) : 0u;

    // B-search: 8 quad rounds resolve top 16 bits; count_cm(>=B) >= 32
    unsigned lo = 0;
    unsigned long long w = 1ULL << 32;
    for (int r = 0; r < 8; ++r) {
      w >>= 2;
      const unsigned wu = (unsigned)w;
      const unsigned m1 = lo + wu, m2 = lo + 2u * wu, m3 = lo + 3u * wu;
      unsigned p = (unsigned)((kA >= m1) + (kB >= m1)) |
                   ((unsigned)((kA >= m2) + (kB >= m2)) << 16);
      unsigned q = (unsigned)((kA >= m3) + (kB >= m3));
      p += __shfl_down(p, 32); q += __shfl_down(q, 32);
      p += __shfl_down(p, 16); q += __shfl_down(q, 16);
      p += __shfl_down(p, 8);  q += __shfl_down(q, 8);
      p += __shfl_down(p, 4);  q += __shfl_down(q, 4);
      p += __shfl_down(p, 2);  q += __shfl_down(q, 2);
      p += __shfl_down(p, 1);  q += __shfl_down(q, 1);
      p = __shfl(p, 0); q = __shfl(q, 0);
      if (q >= (unsigned)TOPK)                  lo = m3;
      else if ((p >> 16) >= (unsigned)TOPK)     lo = m2;
      else if ((p & 0xFFFFu) >= (unsigned)TOPK) lo = m1;
    }
    const unsigned B = lo;

    // eligible chunk list
    if (kA >= B) { const int p = atomicAdd(&s_ne, 1); s_elig[p] = lane; }
    if (lane < NCHUNK - 64 && kB >= B) { const int p = atomicAdd(&s_ne, 1); s_elig[p] = lane + 64; }
    const int ne = __shfl(s_ne, 0);   // wave-internal: s_ne stable after the
                                      // atomics complete; broadcast via lane0
    // scan eligible chunks only (2 chunks per pass across 64 lanes)
    for (int i = (lane >> 5); i < ne; i += 2) {
      const int c  = s_elig[i];
      const int f4 = (c << 5) + (lane & 31);
      const float4 v = zr[f4];
      const int base = f4 << 2;
      const unsigned k0 = fkey(v.x), k1 = fkey(v.y), k2 = fkey(v.z), k3 = fkey(v.w);
      if (k0 >= B) { int p = atomicAdd(&s_cc, 1); if (p < 512) { candk[p] = k0; candi[p] = base; } }
      if (k1 >= B) { int p = atomicAdd(&s_cc, 1); if (p < 512) { candk[p] = k1; candi[p] = base + 1; } }
      if (k2 >= B) { int p = atomicAdd(&s_cc, 1); if (p < 512) { candk[p] = k2; candi[p] = base + 2; } }
      if (k3 >= B) { int p = atomicAdd(&s_cc, 1); if (p < 512) { candk[p] = k3; candi[p] = base + 3; } }
    }
  }
  __syncthreads();
  const int cc = s_cc;
  float4* zw = (float4*)(Z + (size_t)row * N_DIM);

  // ================= phase 2: select (w0) || zero-stream (w1-3) ===========
  if (cc <= 512) {
    if (wid == 0) {
      unsigned k[8];
#pragma unroll
      for (int i = 0; i < 8; ++i) k[i] = (lane + 64 * i < cc) ? candk[lane + 64 * i] : 0u;
      unsigned lo = 0;
      unsigned long long w = 1ULL << 32;
      for (int r = 0; r < 16; ++r) {
        w >>= 2;
        const unsigned wu = (unsigned)w;
        const unsigned m1 = lo + wu, m2 = lo + 2u * wu, m3 = lo + 3u * wu;
        unsigned c1 = 0, c2 = 0, c3 = 0;
#pragma unroll
        for (int i = 0; i < 8; ++i) {
          c1 += (k[i] >= m1); c2 += (k[i] >= m2); c3 += (k[i] >= m3);
        }
        unsigned p = c1 | (c2 << 16), q = c3;
        p += __shfl_down(p, 32); q += __shfl_down(q, 32);
        p += __shfl_down(p, 16); q += __shfl_down(q, 16);
        p += __shfl_down(p, 8);  q += __shfl_down(q, 8);
        p += __shfl_down(p, 4);  q += __shfl_down(q, 4);
        p += __shfl_down(p, 2);  q += __shfl_down(q, 2);
        p += __shfl_down(p, 1);  q += __shfl_down(q, 1);
        p = __shfl(p, 0); q = __shfl(q, 0);
        if (q >= (unsigned)TOPK)                  lo = m3;
        else if ((p >> 16) >= (unsigned)TOPK)     lo = m2;
        else if ((p & 0xFFFFu) >= (unsigned)TOPK) lo = m1;
      }
      const unsigned T = lo;                 // exact 32nd-largest key
      const float thresh = kinv(T);
      for (int i = lane; i < cc; i += 64) {
        const unsigned ck = candk[i];
        if (ck > T) {
          const int p = atomicAdd(&s_nnz, 1);
          if (p < TOPK) { s_col[p] = candi[i]; s_val[p] = kinv(ck) - thresh; }
        }
      }
    } else {
      const float4 z4 = {0.f, 0.f, 0.f, 0.f};
#pragma unroll
      for (int jj = 0; jj < 16; ++jj)
        zw[(wid - 1) * 64 + lane + 192 * jj] = z4;
    }
    __syncthreads();
  } else {
    // ---- rare fallback: exact block-wide quad binsearch on intact row ----
    unsigned lo = 0;
    unsigned long long w = 1ULL << 32;
    for (int r = 0; r < 16; ++r) {
      w >>= 2;
      const unsigned wu = (unsigned)w;
      const unsigned m1 = lo + wu, m2 = lo + 2u * wu, m3 = lo + 3u * wu;
      unsigned c1 = 0, c2 = 0, c3 = 0;
      for (int j = 0; j < 12; ++j) {
        const float4 v = zr[t + 256 * j];
        const unsigned k0 = fkey(v.x), k1 = fkey(v.y), k2 = fkey(v.z), k3 = fkey(v.w);
        c1 += (k0 >= m1) + (k1 >= m1) + (k2 >= m1) + (k3 >= m1);
        c2 += (k0 >= m2) + (k1 >= m2) + (k2 >= m2) + (k3 >= m2);
        c3 += (k0 >= m3) + (k1 >= m3) + (k2 >= m3) + (k3 >= m3);
      }
      unsigned p = c1 | (c2 << 16), q = c3;
      p += __shfl_down(p, 32); q += __shfl_down(q, 32);
      p += __shfl_down(p, 16); q += __shfl_down(q, 16);
      p += __shfl_down(p, 8);  q += __shfl_down(q, 8);
      p += __shfl_down(p, 4);  q += __shfl_down(q, 4);
      p += __shfl_down(p, 2);  q += __shfl_down(q, 2);
      p += __shfl_down(p, 1);  q += __shfl_down(q, 1);
      const int par = r & 1;
      if (lane == 0) { red[par][0][wid] = p; red[par][1][wid] = q; }
      __syncthreads();
      const unsigned P = red[par][0][0] + red[par][0][1] + red[par][0][2] + red[par][0][3];
      const unsigned Q = red[par][1][0] + red[par][1][1] + red[par][1][2] + red[par][1][3];
      if (Q >= (unsigned)TOPK)                  lo = m3;
      else if ((P >> 16) >= (unsigned)TOPK)     lo = m2;
      else if ((P & 0xFFFFu) >= (unsigned)TOPK) lo = m1;
    }
    const unsigned T = lo;
    const float thresh = kinv(T);
    const float4 z4 = {0.f, 0.f, 0.f, 0.f};
    for (int j = 0; j < 12; ++j) {
      const float4 v = zr[t + 256 * j];
      const int base = (t + 256 * j) * 4;
      const unsigned k0 = fkey(v.x), k1 = fkey(v.y), k2 = fkey(v.z), k3 = fkey(v.w);
      if (k0 > T) { int p = atomicAdd(&s_nnz, 1); if (p < TOPK) { s_col[p] = base;     s_val[p] = kinv(k0) - thresh; } }
      if (k1 > T) { int p = atomicAdd(&s_nnz, 1); if (p < TOPK) { s_col[p] = base + 1; s_val[p] = kinv(k1) - thresh; } }
      if (k2 > T) { int p = atomicAdd(&s_nnz, 1); if (p < TOPK) { s_col[p] = base + 2; s_val[p] = kinv(k2) - thresh; } }
      if (k3 > T) { int p = atomicAdd(&s_nnz, 1); if (p < TOPK) { s_col[p] = base + 3; s_val[p] = kinv(k3) - thresh; } }
      zw[t + 256 * j] = z4;
    }
    __syncthreads();
  }

  // ---- scatter the <=31 surviving entries ----
  const int nnz = (s_nnz < TOPK) ? s_nnz : TOPK;
  if (t < nnz) Z[(size_t)row * N_DIM + s_col[t]] = s_val[t];

  // ---- sparse decode, fixed 32-trip (zero-padded) ----
  float a0 = 0.0f, a1 = 0.0f, a2 = 0.0f;
#pragma unroll 8
  for (int j = 0; j < TOPK; ++j) {
    const float v = s_val[j];
    const float* wp = WT + (size_t)s_col[j] * K_DIM;
    a0 += v * wp[t];
    a1 += v * wp[t + 256];
    a2 += v * wp[t + 512];
  }
  float* xr = XR + (size_t)row * K_DIM;
  xr[t]       = a0 + db[t];
  xr[t + 256] = a1 + db[t + 256];
  xr[t + 512] = a2 + db[t + 512];
}

// ---------------------------------------------------------------------------
// Decode fallback (no CMAX workspace): LDS-staged exact quad binsearch
// ---------------------------------------------------------------------------
__device__ __forceinline__ void full_round_l(
    const uint4* zk, unsigned red[][2][4], int t, int lane, int wid, int r,
    unsigned& lo, unsigned long long& w)
{
  w >>= 2;
  const unsigned wu = (unsigned)w;
  const unsigned m1 = lo + wu, m2 = lo + 2u * wu, m3 = lo + 3u * wu;
  unsigned c1 = 0, c2 = 0, c3 = 0;
#pragma unroll
  for (int j = 0; j < 12; ++j) {
    const uint4 k = zk[t + 256 * j];
    c1 += (k.x >= m1) + (k.y >= m1) + (k.z >= m1) + (k.w >= m1);
    c2 += (k.x >= m2) + (k.y >= m2) + (k.z >= m2) + (k.w >= m2);
    c3 += (k.x >= m3) + (k.y >= m3) + (k.z >= m3) + (k.w >= m3);
  }
  unsigned p = c1 | (c2 << 16), q = c3;
  p += __shfl_down(p, 32); q += __shfl_down(q, 32);
  p += __shfl_down(p, 16); q += __shfl_down(q, 16);
  p += __shfl_down(p, 8);  q += __shfl_down(q, 8);
  p += __shfl_down(p, 4);  q += __shfl_down(q, 4);
  p += __shfl_down(p, 2);  q += __shfl_down(q, 2);
  p += __shfl_down(p, 1);  q += __shfl_down(q, 1);
  const int par = r & 1;
  if (lane == 0) { red[par][0][wid] = p; red[par][1][wid] = q; }
  __syncthreads();
  const unsigned P = red[par][0][0] + red[par][0][1] + red[par][0][2] + red[par][0][3];
  const unsigned Q = red[par][1][0] + red[par][1][1] + red[par][1][2] + red[par][1][3];
  if (Q >= (unsigned)TOPK)                lo = m3;
  else if ((P >> 16) >= (unsigned)TOPK)   lo = m2;
  else if ((P & 0xFFFFu) >= (unsigned)TOPK) lo = m1;
}

__global__ __launch_bounds__(256, 3) void topk_select_decode_fb(
    float* Z, const float* __restrict__ WT, const float* __restrict__ DW,
    const float* __restrict__ db, float* __restrict__ XR, int use_wt)
{
  __shared__ uint4 zkey4[N_DIM / 4];
  __shared__ unsigned red[2][2][4];
  __shared__ unsigned cand[256];
  __shared__ unsigned s_T;
  __shared__ int s_cc;
  __shared__ int s_nnz;
  __shared__ int   s_col[TOPK];
  __shared__ float s_val[TOPK];

  const int row  = (int)blockIdx.x;
  const int t    = (int)threadIdx.x;
  const int lane = t & 63;
  const int wid  = t >> 6;

  float4* zv = (float4*)(Z + (size_t)row * N_DIM);

#pragma unroll
  for (int j = 0; j < 12; ++j) {
    const float4 v = zv[t + 256 * j];
    uint4 k;
    k.x = fkey(v.x); k.y = fkey(v.y); k.z = fkey(v.z); k.w = fkey(v.w);
    zkey4[t + 256 * j] = k;
  }
  if (t == 0) { s_nnz = 0; s_cc = 0; }
  if (t < TOPK) { s_col[t] = 0; s_val[t] = 0.0f; }
  __syncthreads();

  unsigned lo = 0;
  unsigned long long w = 1ULL << 32;
  for (int r = 0; r < 8; ++r)
    full_round_l(zkey4, red, t, lane, wid, r, lo, w);

#pragma unroll
  for (int j = 0; j < 12; ++j) {
    const uint4 k = zkey4[t + 256 * j];
    if (k.x >= lo) { int p = atomicAdd(&s_cc, 1); if (p < 256) cand[p] = k.x; }
    if (k.y >= lo) { int p = atomicAdd(&s_cc, 1); if (p < 256) cand[p] = k.y; }
    if (k.z >= lo) { int p = atomicAdd(&s_cc, 1); if (p < 256) cand[p] = k.z; }
    if (k.w >= lo) { int p = atomicAdd(&s_cc, 1); if (p < 256) cand[p] = k.w; }
  }
  __syncthreads();
  const int cc = s_cc;

  if (cc <= 256) {
    if (wid == 0) {
      const unsigned k0 = (lane       < cc) ? cand[lane]       : 0u;
      const unsigned k1 = (lane + 64  < cc) ? cand[lane + 64]  : 0u;
      const unsigned k2 = (lane + 128 < cc) ? cand[lane + 128] : 0u;
      const unsigned k3 = (lane + 192 < cc) ? cand[lane + 192] : 0u;
      for (int r = 8; r < 16; ++r) {
        w >>= 2;
        const unsigned wu = (unsigned)w;
        const unsigned m1 = lo + wu, m2 = lo + 2u * wu, m3 = lo + 3u * wu;
        unsigned c1 = (k0 >= m1) + (k1 >= m1) + (k2 >= m1) + (k3 >= m1);
        unsigned c2 = (k0 >= m2) + (k1 >= m2) + (k2 >= m2) + (k3 >= m2);
        unsigned c3 = (k0 >= m3) + (k1 >= m3) + (k2 >= m3) + (k3 >= m3);
        unsigned p = c1 | (c2 << 16), q = c3;
        p += __shfl_down(p, 32); q += __shfl_down(q, 32);
        p += __shfl_down(p, 16); q += __shfl_down(q, 16);
        p += __shfl_down(p, 8);  q += __shfl_down(q, 8);
        p += __shfl_down(p, 4);  q += __shfl_down(q, 4);
        p += __shfl_down(p, 2);  q += __shfl_down(q, 2);
        p += __shfl_down(p, 1);  q += __shfl_down(q, 1);
        p = __shfl(p, 0); q = __shfl(q, 0);
        if (q >= (unsigned)TOPK)                  lo = m3;
        else if ((p >> 16) >= (unsigned)TOPK)     lo = m2;
        else if ((p & 0xFFFFu) >= (unsigned)TOPK) lo = m1;
      }
      if (lane == 0) s_T = lo;
    }
  } else {
    for (int r = 8; r < 16; ++r)
      full_round_l(zkey4, red, t, lane, wid, r, lo, w);
    if (t == 0) s_T = lo;
  }
  __syncthreads();
  const unsigned T = s_T;
  const float thresh = kinv(T);

#define COMPF(KF, OFS, OF) {                                                  \
      float v = 0.0f;                                                         \
      if (KF > T) {                                                           \
        v = kinv(KF) - thresh;                                                \
        const int p = atomicAdd(&s_nnz, 1);                                   \
        if (p < TOPK) { s_col[p] = base + OFS; s_val[p] = v; }                \
      }                                                                       \
      o.OF = v; }
#pragma unroll
  for (int j = 0; j < 12; ++j) {
    const uint4 k = zkey4[t + 256 * j];
    const int base = (t + 256 * j) * 4;
    float4 o;
    COMPF(k.x, 0, x)
    COMPF(k.y, 1, y)
    COMPF(k.z, 2, z)
    COMPF(k.w, 3, w)
    zv[t + 256 * j] = o;
  }
#undef COMPF
  __syncthreads();

  float a0 = 0.0f, a1 = 0.0f, a2 = 0.0f;
  if (use_wt) {
#pragma unroll 8
    for (int j = 0; j < TOPK; ++j) {
      const float v = s_val[j];
      const float* wp = WT + (size_t)s_col[j] * K_DIM;
      a0 += v * wp[t];
      a1 += v * wp[t + 256];
      a2 += v * wp[t + 512];
    }
  } else {
#pragma unroll 8
    for (int j = 0; j < TOPK; ++j) {
      const float v = s_val[j];
      const int col = s_col[j];
      a0 += v * DW[(size_t)(t)       * N_DIM + col];
      a1 += v * DW[(size_t)(t + 256) * N_DIM + col];
      a2 += v * DW[(size_t)(t + 512) * N_DIM + col];
    }
  }
  float* xr = XR + (size_t)row * K_DIM;
  xr[t]       = a0 + db[t];
  xr[t + 256] = a1 + db[t + 256];
  xr[t + 512] = a2 + db[t + 512];
}

// ---------------------------------------------------------------------------
extern "C" void kernel_launch(void* const* d_in, const int* in_sizes, int n_in,
                              void* d_out, int out_size, void* d_ws, size_t ws_size,
                              hipStream_t stream)
{
  (void)in_sizes; (void)n_in; (void)out_size;

  const float* x     = (const float*)d_in[0];
  const float* enc_w = (const float*)d_in[1];
  const float* enc_b = (const float*)d_in[2];
  const float* dec_w = (const float*)d_in[3];
  const float* dec_b = (const float*)d_in[4];
  // d_in[5] = k (constant 32, hardcoded as TOPK)

  float* out     = (float*)d_out;
  float* x_recon = out;                            // M*K floats
  float* z_sp    = out + (size_t)M_DIM * K_DIM;    // M*N floats

  const size_t WT_BYTES = (size_t)N_DIM * K_DIM * sizeof(float);      // 37.75 MB
  const size_t XPLANE   = (size_t)M_DIM * K_DIM * sizeof(unsigned short);
  const size_t WPLANE   = (size_t)N_DIM * K_DIM * sizeof(unsigned short);
  const size_t FULL     = WT_BYTES + 2 * XPLANE + 2 * WPLANE;         // 120 MiB
  const size_t CMAX_B   = (size_t)M_DIM * NCHUNK * sizeof(float);     // 6.3 MB
  const size_t FULL2    = FULL + CMAX_B;                              // 126 MiB

  char* ws = (char*)d_ws;
  const int use_wt   = (ws_size >= WT_BYTES) ? 1 : 0;
  const int use_mfma = (ws_size >= FULL) ? 1 : 0;
  const int use_cmax = (ws_size >= FULL2) ? 1 : 0;

  float*          WT   = (float*)ws;
  unsigned short* xhi  = (unsigned short*)(ws + WT_BYTES);
  unsigned short* xlo  = (unsigned short*)(ws + WT_BYTES + XPLANE);
  unsigned short* whi  = (unsigned short*)(ws + WT_BYTES + 2 * XPLANE);
  unsigned short* wlo  = (unsigned short*)(ws + WT_BYTES + 2 * XPLANE + WPLANE);
  float*          CMAX = (float*)(ws + FULL);

  if (use_wt || use_mfma)
    TopKSparseAutoencoder_51917564674099_prep<<<10752, 256, 0, stream>>>(
        x, enc_w, dec_w, xhi, xlo, whi, wlo, WT, use_wt, use_mfma);

  if (use_mfma) {
    dim3 tg(N_DIM / 128, M_DIM / 128);   // (96, 128)
    TopKSparseAutoencoder_51917564674099_kernel<<<tg, 256, 0, stream>>>(
        xhi, xlo, whi, wlo, enc_b, z_sp, CMAX, use_cmax);
  } else {
    dim3 tb(16, 16);
    dim3 tg(N_DIM / 128, M_DIM / 128);
    enc_gemm_f32_fb<<<tg, tb, 0, stream>>>(x, enc_w, enc_b, z_sp);
  }

  if (use_cmax)
    TopKSparseAutoencoder_51917564674099_zdecode<<<M_DIM, 256, 0, stream>>>(
        z_sp, CMAX, WT, dec_b, x_recon);
  else
    topk_select_decode_fb<<<M_DIM, 256, 0, stream>>>(
        z_sp, WT, dec_w, dec_b, x_recon, use_wt);
}

// Round 5
// 2170.042 us; speedup vs baseline: 1.0366x; 1.0366x over previous
//
#include <hip/hip_runtime.h>

#define M_DIM 16384
#define K_DIM 768
#define N_DIM 12288
#define TOPK  32
#define NCHUNK (N_DIM / 128)   // 96 col-chunks per row

typedef float f32x4 __attribute__((ext_vector_type(4)));
typedef short s16x8 __attribute__((ext_vector_type(8)));

__device__ __forceinline__ unsigned f2u(float f) {
  union { float f; unsigned u; } v; v.f = f; return v.u;
}
__device__ __forceinline__ float u2f(unsigned u) {
  union { unsigned u; float f; } v; v.u = u; return v.f;
}
__device__ __forceinline__ unsigned fkey(float f) {
  const unsigned u = f2u(f);
  return u ^ (unsigned)(((int)u >> 31) | 0x80000000);
}
__device__ __forceinline__ float kinv(unsigned k) {
  return u2f((k & 0x80000000u) ? (k ^ 0x80000000u) : ~k);
}
__device__ __forceinline__ unsigned short bf16_rne(float f) {
  unsigned u = f2u(f);
  return (unsigned short)((u + 0x7FFFu + ((u >> 16) & 1u)) >> 16);
}

// ---------------------------------------------------------------------------
// Prep (fused): dec_w transpose + bf16 hi/lo splits of x and enc_w.
// ---------------------------------------------------------------------------
__global__ __launch_bounds__(256) void TopKSparseAutoencoder_51917564674099_prep(
    const float* __restrict__ x, const float* __restrict__ w,
    const float* __restrict__ dw,
    unsigned short* __restrict__ xhi, unsigned short* __restrict__ xlo,
    unsigned short* __restrict__ whi, unsigned short* __restrict__ wlo,
    float* __restrict__ WT, int do_t, int do_s)
{
  __shared__ float tile[32][33];
  const int b = (int)blockIdx.x;
  const int t = (int)threadIdx.x;

  if (b < 9216) {
    if (!do_t) return;
    const int bx = b % (N_DIM / 32);
    const int by = b / (N_DIM / 32);
    const int tx = t & 31, ty = t >> 5;           // 32 x 8
#pragma unroll
    for (int j = 0; j < 32; j += 8)
      tile[ty + j][tx] = dw[(size_t)(by * 32 + ty + j) * N_DIM + bx * 32 + tx];
    __syncthreads();
#pragma unroll
    for (int j = 0; j < 32; j += 8)
      WT[(size_t)(bx * 32 + ty + j) * K_DIM + by * 32 + tx] = tile[tx][ty + j];
    return;
  }
  if (!do_s) return;

  const float* src; unsigned short* dh; unsigned short* dl; int i, stride, n4;
  if (b < 9216 + 1024) {
    src = x; dh = xhi; dl = xlo;
    i = (b - 9216) * 256 + t; stride = 1024 * 256; n4 = M_DIM * K_DIM / 4;
  } else {
    src = w; dh = whi; dl = wlo;
    i = (b - 10240) * 256 + t; stride = 512 * 256; n4 = N_DIM * K_DIM / 4;
  }
  for (; i < n4; i += stride) {
    const float4 v = ((const float4*)src)[i];
    ushort4 h, l;
    h.x = bf16_rne(v.x); h.y = bf16_rne(v.y); h.z = bf16_rne(v.z); h.w = bf16_rne(v.w);
    l.x = bf16_rne(v.x - u2f((unsigned)h.x << 16));
    l.y = bf16_rne(v.y - u2f((unsigned)h.y << 16));
    l.z = bf16_rne(v.z - u2f((unsigned)h.z << 16));
    l.w = bf16_rne(v.w - u2f((unsigned)h.w << 16));
    ((ushort4*)dh)[i] = h;
    ((ushort4*)dl)[i] = l;
  }
}

// ---------------------------------------------------------------------------
// Main GEMM: z = x @ enc_w^T + enc_b via bf16x3 MFMA (fp32-equivalent).
// REVERTED to the R3 single-buffer form (1025 us, MfmaUtil 41% = m97-structure
// ceiling).  R4's dbuf regressed: __syncthreads drains vmcnt(0) including the
// prefetch, and 64KB LDS cut residency 3->2 blocks/CU.
// ---------------------------------------------------------------------------
__device__ __forceinline__ void mfma16(f32x4& d, s16x8 a, s16x8 b) {
  asm("v_mfma_f32_16x16x32_bf16 %0, %1, %2, %0" : "+v"(d) : "v"(a), "v"(b));
}

#define GL16(g, l) __builtin_amdgcn_global_load_lds(                      \
    (const __attribute__((address_space(1))) void*)(g),                   \
    (__attribute__((address_space(3))) void*)(l), 16, 0, 0)

__global__ __launch_bounds__(256, 2) void TopKSparseAutoencoder_51917564674099_kernel(
    const unsigned short* __restrict__ Ahi, const unsigned short* __restrict__ Alo,
    const unsigned short* __restrict__ Bhi, const unsigned short* __restrict__ Blo,
    const float* __restrict__ bias, float* __restrict__ Z,
    float* __restrict__ cmax, int do_cmax)
{
  __shared__ unsigned short lds[4][128][32];   // 32 KB
  __shared__ float cmx[128][2];                // chunk-max combine

  const int t    = (int)threadIdx.x;
  const int wid  = t >> 6;
  const int lane = t & 63;

  const int bid  = (int)(blockIdx.y * gridDim.x + blockIdx.x);
  const int bswz = (bid & 7) * (12288 / 8) + (bid >> 3);
  const int n0   = (bswz % 96) * 128;
  const int m0   = (bswz / 96) * 128;

  const int rr  = lane >> 2;
  const int kq  = lane & 3;
  const int rt0 = wid * 32 + rr;
  const int rt1 = rt0 + 16;
  const int kc0 = (kq ^ ((rt0 >> 1) & 3)) * 8;
  const int kc1 = (kq ^ ((rt1 >> 1) & 3)) * 8;
  const size_t offA0 = (size_t)(m0 + rt0) * K_DIM + kc0;
  const size_t offA1 = (size_t)(m0 + rt1) * K_DIM + kc1;
  const size_t offB0 = (size_t)(n0 + rt0) * K_DIM + kc0;
  const size_t offB1 = (size_t)(n0 + rt1) * K_DIM + kc1;

  const int wm = (wid >> 1) * 64;
  const int wn = (wid & 1) * 64;
  const int lr = lane & 15;
  const int lc = lane >> 4;

  f32x4 acc[4][4];
#pragma unroll
  for (int i = 0; i < 4; ++i)
#pragma unroll
    for (int j = 0; j < 4; ++j) acc[i][j] = (f32x4){0.f, 0.f, 0.f, 0.f};

  for (int k0 = 0; k0 < K_DIM; k0 += 32) {
    GL16(Ahi + offA0 + k0, &lds[0][wid * 32][0]);
    GL16(Ahi + offA1 + k0, &lds[0][wid * 32 + 16][0]);
    GL16(Alo + offA0 + k0, &lds[1][wid * 32][0]);
    GL16(Alo + offA1 + k0, &lds[1][wid * 32 + 16][0]);
    GL16(Bhi + offB0 + k0, &lds[2][wid * 32][0]);
    GL16(Bhi + offB1 + k0, &lds[2][wid * 32 + 16][0]);
    GL16(Blo + offB0 + k0, &lds[3][wid * 32][0]);
    GL16(Blo + offB1 + k0, &lds[3][wid * 32 + 16][0]);
    __syncthreads();

    s16x8 ah[4], al[4], bh[4], bl[4];
#pragma unroll
    for (int i = 0; i < 4; ++i) {
      const int r = wm + i * 16 + lr;
      const int p = (lc ^ ((r >> 1) & 3)) * 8;
      ah[i] = *(const s16x8*)&lds[0][r][p];
      al[i] = *(const s16x8*)&lds[1][r][p];
    }
#pragma unroll
    for (int j = 0; j < 4; ++j) {
      const int r = wn + j * 16 + lr;
      const int p = (lc ^ ((r >> 1) & 3)) * 8;
      bh[j] = *(const s16x8*)&lds[2][r][p];
      bl[j] = *(const s16x8*)&lds[3][r][p];
    }
#pragma unroll
    for (int i = 0; i < 4; ++i)
#pragma unroll
      for (int j = 0; j < 4; ++j) {
        mfma16(acc[i][j], ah[i], bh[j]);
        mfma16(acc[i][j], ah[i], bl[j]);
        mfma16(acc[i][j], al[i], bh[j]);
      }
    __syncthreads();
  }

  asm volatile("s_nop 7\n\ts_nop 7" :::);

  float mx[4][4];
#pragma unroll
  for (int i = 0; i < 4; ++i)
#pragma unroll
    for (int q = 0; q < 4; ++q) mx[i][q] = -3.4e38f;

#pragma unroll
  for (int j = 0; j < 4; ++j) {
    const int col = n0 + wn + j * 16 + lr;
    const float bb = bias[col];
#pragma unroll
    for (int i = 0; i < 4; ++i) {
      const int r0 = m0 + wm + i * 16 + lc * 4;
#pragma unroll
      for (int q = 0; q < 4; ++q) {
        const float val = acc[i][j][q] + bb;
        Z[(size_t)(r0 + q) * N_DIM + col] = val;
        mx[i][q] = fmaxf(mx[i][q], val);
      }
    }
  }

  if (do_cmax) {
#pragma unroll
    for (int s = 1; s < 16; s <<= 1)
#pragma unroll
      for (int i = 0; i < 4; ++i)
#pragma unroll
        for (int q = 0; q < 4; ++q)
          mx[i][q] = fmaxf(mx[i][q], __shfl_xor(mx[i][q], s));
    if (lr == 0) {
#pragma unroll
      for (int i = 0; i < 4; ++i)
#pragma unroll
        for (int q = 0; q < 4; ++q)
          cmx[wm + i * 16 + lc * 4 + q][wid & 1] = mx[i][q];
    }
    __syncthreads();
    if (t < 128)
      cmax[(size_t)(m0 + t) * NCHUNK + (n0 >> 7)] = fmaxf(cmx[t][0], cmx[t][1]);
  }
}

// ---------------------------------------------------------------------------
// fp32 VALU GEMM fallback (workspace too small for MFMA path)
// ---------------------------------------------------------------------------
__global__ void enc_gemm_f32_fb(
    const float* A, const float* B, const float* bias, float* Z)
{
  __shared__ float As[32][132];
  __shared__ float Bs[32][132];

  const int tx = (int)threadIdx.x;
  const int ty = (int)threadIdx.y;
  const int t  = ty * 16 + tx;
  const int n0 = (int)blockIdx.x * 128;
  const int m0 = (int)blockIdx.y * 128;
  const int r = t >> 1;
  const int h = (t & 1) * 16;

  float c[8][8];
#pragma unroll
  for (int i = 0; i < 8; ++i)
#pragma unroll
    for (int j = 0; j < 8; ++j) c[i][j] = 0.0f;

  for (int k0 = 0; k0 < K_DIM; k0 += 32) {
    const float* pa = A + (size_t)(m0 + r) * K_DIM + k0 + h;
    const float* pb = B + (size_t)(n0 + r) * K_DIM + k0 + h;
    float fa[16], fb[16];
#pragma unroll
    for (int j = 0; j < 16; ++j) fa[j] = pa[j];
#pragma unroll
    for (int j = 0; j < 16; ++j) fb[j] = pb[j];
#pragma unroll
    for (int j = 0; j < 16; ++j) As[h + j][r] = fa[j];
#pragma unroll
    for (int j = 0; j < 16; ++j) Bs[h + j][r] = fb[j];
    __syncthreads();

    for (int kk = 0; kk < 32; ++kk) {
      float av[8], bv[8];
#pragma unroll
      for (int i = 0; i < 8; ++i) av[i] = As[kk][ty * 8 + i];
#pragma unroll
      for (int j = 0; j < 8; ++j) bv[j] = Bs[kk][tx * 8 + j];
#pragma unroll
      for (int i = 0; i < 8; ++i)
#pragma unroll
        for (int j = 0; j < 8; ++j) c[i][j] += av[i] * bv[j];
    }
    __syncthreads();
  }

#pragma unroll
  for (int j = 0; j < 8; ++j) {
    const int col = n0 + tx * 8 + j;
    const float bb = bias[col];
#pragma unroll
    for (int i = 0; i < 8; ++i)
      Z[(size_t)(m0 + ty * 8 + i) * N_DIM + col] = c[i][j] + bb;
  }
}

// ---------------------------------------------------------------------------
// Fast decode v3: WAVE-AUTONOMOUS.  One row per wave, 4 rows/block, grid 4096,
// ZERO block barriers.  Each wave: B-search over 96 chunk maxes -> scan only
// eligible chunks -> issue zero-stream early -> exact candidate select (shfl
// rounds, under the draining stores) -> vmcnt(0) -> scatter -> f32x4 gather.
// All 4 waves always working; TLP hides HBM latency (old design idled 3/4
// waves at barriers -> ~1.1 ms invariant across 4 decode algorithms).
// ---------------------------------------------------------------------------
__global__ __launch_bounds__(256, 4) void TopKSparseAutoencoder_51917564674099_zdecode(
    float* Z, const float* __restrict__ CMAX, const float* __restrict__ WT,
    const float* __restrict__ db, float* __restrict__ XR)
{
  __shared__ unsigned candk[4][256];
  __shared__ int      candi[4][256];
  __shared__ short    s_elig[4][NCHUNK];
  __shared__ int s_ne[4], s_cc[4], s_nnz[4];
  __shared__ int   s_col[4][TOPK];
  __shared__ float s_val[4][TOPK];

  const int t    = (int)threadIdx.x;
  const int lane = t & 63;
  const int wid  = t >> 6;
  const int row  = (int)blockIdx.x * 4 + wid;

  if (lane == 0) { s_ne[wid] = 0; s_cc[wid] = 0; s_nnz[wid] = 0; }
  if (lane < TOPK) { s_col[wid][lane] = 0; s_val[wid][lane] = 0.0f; }

  const f32x4* zr = (const f32x4*)(Z + (size_t)row * N_DIM);
  f32x4*       zw = (f32x4*)(Z + (size_t)row * N_DIM);

  // ---- B-search over 96 chunk maxes (8 quad rounds -> top 16 bits) ----
  const unsigned kA = fkey(CMAX[(size_t)row * NCHUNK + lane]);
  const unsigned kB = (lane < NCHUNK - 64) ? fkey(CMAX[(size_t)row * NCHUNK + 64 + lane]) : 0u;
  unsigned lo = 0;
  unsigned long long w = 1ULL << 32;
  for (int r = 0; r < 8; ++r) {
    w >>= 2;
    const unsigned wu = (unsigned)w;
    const unsigned m1 = lo + wu, m2 = lo + 2u * wu, m3 = lo + 3u * wu;
    unsigned p = (unsigned)((kA >= m1) + (kB >= m1)) |
                 ((unsigned)((kA >= m2) + (kB >= m2)) << 16);
    unsigned q = (unsigned)((kA >= m3) + (kB >= m3));
    p += __shfl_down(p, 32); q += __shfl_down(q, 32);
    p += __shfl_down(p, 16); q += __shfl_down(q, 16);
    p += __shfl_down(p, 8);  q += __shfl_down(q, 8);
    p += __shfl_down(p, 4);  q += __shfl_down(q, 4);
    p += __shfl_down(p, 2);  q += __shfl_down(q, 2);
    p += __shfl_down(p, 1);  q += __shfl_down(q, 1);
    p = __shfl(p, 0); q = __shfl(q, 0);
    if (q >= (unsigned)TOPK)                  lo = m3;
    else if ((p >> 16) >= (unsigned)TOPK)     lo = m2;
    else if ((p & 0xFFFFu) >= (unsigned)TOPK) lo = m1;
  }
  const unsigned B = lo;

  // ---- eligible chunk list (count >= 32 by construction) ----
  if (kA >= B) { const int p = atomicAdd(&s_ne[wid], 1); s_elig[wid][p] = (short)lane; }
  if (lane < NCHUNK - 64 && kB >= B) {
    const int p = atomicAdd(&s_ne[wid], 1); s_elig[wid][p] = (short)(lane + 64);
  }
  const int ne = s_ne[wid];

  // ---- scan eligible chunks only (2 chunks/pass, 32 lanes each) ----
  for (int i = (lane >> 5); i < ne; i += 2) {
    const int c  = (int)s_elig[wid][i];
    const int f4 = (c << 5) + (lane & 31);
    const f32x4 v = zr[f4];
    const int base = f4 << 2;
    const unsigned k0 = fkey(v[0]), k1 = fkey(v[1]), k2 = fkey(v[2]), k3 = fkey(v[3]);
    if (k0 >= B) { int p = atomicAdd(&s_cc[wid], 1); if (p < 256) { candk[wid][p] = k0; candi[wid][p] = base; } }
    if (k1 >= B) { int p = atomicAdd(&s_cc[wid], 1); if (p < 256) { candk[wid][p] = k1; candi[wid][p] = base + 1; } }
    if (k2 >= B) { int p = atomicAdd(&s_cc[wid], 1); if (p < 256) { candk[wid][p] = k2; candi[wid][p] = base + 2; } }
    if (k3 >= B) { int p = atomicAdd(&s_cc[wid], 1); if (p < 256) { candk[wid][p] = k3; candi[wid][p] = base + 3; } }
  }
  const int cc = s_cc[wid];
  const f32x4 z4 = (f32x4){0.f, 0.f, 0.f, 0.f};

  if (cc <= 256) {
    // issue the full-row zero-stream NOW; drains under the select rounds
#pragma unroll 8
    for (int jj = 0; jj < 48; ++jj) zw[lane + 64 * jj] = z4;

    // exact select over candidates (counts match the full row for probes
    // >= B; probes < B report >=32 in both -> exact 32nd-largest)
    unsigned k[4];
#pragma unroll
    for (int i = 0; i < 4; ++i) k[i] = (lane + 64 * i < cc) ? candk[wid][lane + 64 * i] : 0u;
    lo = 0; w = 1ULL << 32;
    for (int r = 0; r < 16; ++r) {
      w >>= 2;
      const unsigned wu = (unsigned)w;
      const unsigned m1 = lo + wu, m2 = lo + 2u * wu, m3 = lo + 3u * wu;
      unsigned c1 = 0, c2 = 0, c3 = 0;
#pragma unroll
      for (int i = 0; i < 4; ++i) { c1 += (k[i] >= m1); c2 += (k[i] >= m2); c3 += (k[i] >= m3); }
      unsigned p = c1 | (c2 << 16), q = c3;
      p += __shfl_down(p, 32); q += __shfl_down(q, 32);
      p += __shfl_down(p, 16); q += __shfl_down(q, 16);
      p += __shfl_down(p, 8);  q += __shfl_down(q, 8);
      p += __shfl_down(p, 4);  q += __shfl_down(q, 4);
      p += __shfl_down(p, 2);  q += __shfl_down(q, 2);
      p += __shfl_down(p, 1);  q += __shfl_down(q, 1);
      p = __shfl(p, 0); q = __shfl(q, 0);
      if (q >= (unsigned)TOPK)                  lo = m3;
      else if ((p >> 16) >= (unsigned)TOPK)     lo = m2;
      else if ((p & 0xFFFFu) >= (unsigned)TOPK) lo = m1;
    }
    const unsigned T = lo;
    const float thresh = kinv(T);
    for (int i = lane; i < cc; i += 64) {
      const unsigned ck = candk[wid][i];
      if (ck > T) {
        const int p = atomicAdd(&s_nnz[wid], 1);
        if (p < TOPK) { s_col[wid][p] = candi[wid][i]; s_val[wid][p] = kinv(ck) - thresh; }
      }
    }
  } else {
    // ---- rare fallback (ties): exact wave-level search on intact row ----
    lo = 0; w = 1ULL << 32;
    for (int r = 0; r < 16; ++r) {
      w >>= 2;
      const unsigned wu = (unsigned)w;
      const unsigned m1 = lo + wu, m2 = lo + 2u * wu, m3 = lo + 3u * wu;
      unsigned c1 = 0, c2 = 0, c3 = 0;
      for (int j = 0; j < 48; ++j) {
        const f32x4 v = zr[lane + 64 * j];
        const unsigned k0 = fkey(v[0]), k1 = fkey(v[1]), k2 = fkey(v[2]), k3 = fkey(v[3]);
        c1 += (k0 >= m1) + (k1 >= m1) + (k2 >= m1) + (k3 >= m1);
        c2 += (k0 >= m2) + (k1 >= m2) + (k2 >= m2) + (k3 >= m2);
        c3 += (k0 >= m3) + (k1 >= m3) + (k2 >= m3) + (k3 >= m3);
      }
      unsigned p = c1 | (c2 << 16), q = c3;
      p += __shfl_down(p, 32); q += __shfl_down(q, 32);
      p += __shfl_down(p, 16); q += __shfl_down(q, 16);
      p += __shfl_down(p, 8);  q += __shfl_down(q, 8);
      p += __shfl_down(p, 4);  q += __shfl_down(q, 4);
      p += __shfl_down(p, 2);  q += __shfl_down(q, 2);
      p += __shfl_down(p, 1);  q += __shfl_down(q, 1);
      p = __shfl(p, 0); q = __shfl(q, 0);
      if (q >= (unsigned)TOPK)                  lo = m3;
      else if ((p >> 16) >= (unsigned)TOPK)     lo = m2;
      else if ((p & 0xFFFFu) >= (unsigned)TOPK) lo = m1;
    }
    const unsigned T = lo;
    const float thresh = kinv(T);
    for (int j = 0; j < 48; ++j) {
      const f32x4 v = zr[lane + 64 * j];
      const int base = (lane + 64 * j) * 4;
      const unsigned k0 = fkey(v[0]), k1 = fkey(v[1]), k2 = fkey(v[2]), k3 = fkey(v[3]);
      if (k0 > T) { int p = atomicAdd(&s_nnz[wid], 1); if (p < TOPK) { s_col[wid][p] = base;     s_val[wid][p] = kinv(k0) - thresh; } }
      if (k1 > T) { int p = atomicAdd(&s_nnz[wid], 1); if (p < TOPK) { s_col[wid][p] = base + 1; s_val[wid][p] = kinv(k1) - thresh; } }
      if (k2 > T) { int p = atomicAdd(&s_nnz[wid], 1); if (p < TOPK) { s_col[wid][p] = base + 2; s_val[wid][p] = kinv(k2) - thresh; } }
      if (k3 > T) { int p = atomicAdd(&s_nnz[wid], 1); if (p < TOPK) { s_col[wid][p] = base + 3; s_val[wid][p] = kinv(k3) - thresh; } }
      zw[lane + 64 * j] = z4;   // own elements: read above, then zeroed
    }
  }

  // zero-writes must land before the scatter overwrites top-k positions
  asm volatile("s_waitcnt vmcnt(0)" ::: "memory");
  const int nnz = (s_nnz[wid] < TOPK) ? s_nnz[wid] : TOPK;
  if (lane < nnz) Z[(size_t)row * N_DIM + s_col[wid][lane]] = s_val[wid][lane];

  // ---- sparse decode: f32x4 gather, fixed 32-trip (zero-padded) ----
  const f32x4* WT4 = (const f32x4*)WT;
  f32x4 a0 = z4, a1 = z4, a2 = z4;
#pragma unroll 4
  for (int j = 0; j < TOPK; ++j) {
    const float v = s_val[wid][j];
    const size_t base = (size_t)s_col[wid][j] * (K_DIM / 4);
    const f32x4 w0 = WT4[base + lane];
    const f32x4 w1 = WT4[base + 64 + lane];
    const f32x4 w2 = WT4[base + 128 + lane];
    a0 += w0 * v;
    a1 += w1 * v;
    a2 += w2 * v;
  }
  const f32x4* db4 = (const f32x4*)db;
  f32x4* xr4 = (f32x4*)(XR + (size_t)row * K_DIM);
  xr4[lane]        = a0 + db4[lane];
  xr4[64 + lane]   = a1 + db4[64 + lane];
  xr4[128 + lane]  = a2 + db4[128 + lane];
}

// ---------------------------------------------------------------------------
// Decode fallback (no CMAX workspace): LDS-staged exact quad binsearch
// ---------------------------------------------------------------------------
__device__ __forceinline__ void full_round_l(
    const uint4* zk, unsigned red[][2][4], int t, int lane, int wid, int r,
    unsigned& lo, unsigned long long& w)
{
  w >>= 2;
  const unsigned wu = (unsigned)w;
  const unsigned m1 = lo + wu, m2 = lo + 2u * wu, m3 = lo + 3u * wu;
  unsigned c1 = 0, c2 = 0, c3 = 0;
#pragma unroll
  for (int j = 0; j < 12; ++j) {
    const uint4 k = zk[t + 256 * j];
    c1 += (k.x >= m1) + (k.y >= m1) + (k.z >= m1) + (k.w >= m1);
    c2 += (k.x >= m2) + (k.y >= m2) + (k.z >= m2) + (k.w >= m2);
    c3 += (k.x >= m3) + (k.y >= m3) + (k.z >= m3) + (k.w >= m3);
  }
  unsigned p = c1 | (c2 << 16), q = c3;
  p += __shfl_down(p, 32); q += __shfl_down(q, 32);
  p += __shfl_down(p, 16); q += __shfl_down(q, 16);
  p += __shfl_down(p, 8);  q += __shfl_down(q, 8);
  p += __shfl_down(p, 4);  q += __shfl_down(q, 4);
  p += __shfl_down(p, 2);  q += __shfl_down(q, 2);
  p += __shfl_down(p, 1);  q += __shfl_down(q, 1);
  const int par = r & 1;
  if (lane == 0) { red[par][0][wid] = p; red[par][1][wid] = q; }
  __syncthreads();
  const unsigned P = red[par][0][0] + red[par][0][1] + red[par][0][2] + red[par][0][3];
  const unsigned Q = red[par][1][0] + red[par][1][1] + red[par][1][2] + red[par][1][3];
  if (Q >= (unsigned)TOPK)                lo = m3;
  else if ((P >> 16) >= (unsigned)TOPK)   lo = m2;
  else if ((P & 0xFFFFu) >= (unsigned)TOPK) lo = m1;
}

__global__ __launch_bounds__(256, 3) void topk_select_decode_fb(
    float* Z, const float* __restrict__ WT, const float* __restrict__ DW,
    const float* __restrict__ db, float* __restrict__ XR, int use_wt)
{
  __shared__ uint4 zkey4[N_DIM / 4];
  __shared__ unsigned red[2][2][4];
  __shared__ unsigned cand[256];
  __shared__ unsigned s_T;
  __shared__ int s_cc;
  __shared__ int s_nnz;
  __shared__ int   s_col[TOPK];
  __shared__ float s_val[TOPK];

  const int row  = (int)blockIdx.x;
  const int t    = (int)threadIdx.x;
  const int lane = t & 63;
  const int wid  = t >> 6;

  float4* zv = (float4*)(Z + (size_t)row * N_DIM);

#pragma unroll
  for (int j = 0; j < 12; ++j) {
    const float4 v = zv[t + 256 * j];
    uint4 k;
    k.x = fkey(v.x); k.y = fkey(v.y); k.z = fkey(v.z); k.w = fkey(v.w);
    zkey4[t + 256 * j] = k;
  }
  if (t == 0) { s_nnz = 0; s_cc = 0; }
  if (t < TOPK) { s_col[t] = 0; s_val[t] = 0.0f; }
  __syncthreads();

  unsigned lo = 0;
  unsigned long long w = 1ULL << 32;
  for (int r = 0; r < 8; ++r)
    full_round_l(zkey4, red, t, lane, wid, r, lo, w);

#pragma unroll
  for (int j = 0; j < 12; ++j) {
    const uint4 k = zkey4[t + 256 * j];
    if (k.x >= lo) { int p = atomicAdd(&s_cc, 1); if (p < 256) cand[p] = k.x; }
    if (k.y >= lo) { int p = atomicAdd(&s_cc, 1); if (p < 256) cand[p] = k.y; }
    if (k.z >= lo) { int p = atomicAdd(&s_cc, 1); if (p < 256) cand[p] = k.z; }
    if (k.w >= lo) { int p = atomicAdd(&s_cc, 1); if (p < 256) cand[p] = k.w; }
  }
  __syncthreads();
  const int cc = s_cc;

  if (cc <= 256) {
    if (wid == 0) {
      const unsigned k0 = (lane       < cc) ? cand[lane]       : 0u;
      const unsigned k1 = (lane + 64  < cc) ? cand[lane + 64]  : 0u;
      const unsigned k2 = (lane + 128 < cc) ? cand[lane + 128] : 0u;
      const unsigned k3 = (lane + 192 < cc) ? cand[lane + 192] : 0u;
      for (int r = 8; r < 16; ++r) {
        w >>= 2;
        const unsigned wu = (unsigned)w;
        const unsigned m1 = lo + wu, m2 = lo + 2u * wu, m3 = lo + 3u * wu;
        unsigned c1 = (k0 >= m1) + (k1 >= m1) + (k2 >= m1) + (k3 >= m1);
        unsigned c2 = (k0 >= m2) + (k1 >= m2) + (k2 >= m2) + (k3 >= m2);
        unsigned c3 = (k0 >= m3) + (k1 >= m3) + (k2 >= m3) + (k3 >= m3);
        unsigned p = c1 | (c2 << 16), q = c3;
        p += __shfl_down(p, 32); q += __shfl_down(q, 32);
        p += __shfl_down(p, 16); q += __shfl_down(q, 16);
        p += __shfl_down(p, 8);  q += __shfl_down(q, 8);
        p += __shfl_down(p, 4);  q += __shfl_down(q, 4);
        p += __shfl_down(p, 2);  q += __shfl_down(q, 2);
        p += __shfl_down(p, 1);  q += __shfl_down(q, 1);
        p = __shfl(p, 0); q = __shfl(q, 0);
        if (q >= (unsigned)TOPK)                  lo = m3;
        else if ((p >> 16) >= (unsigned)TOPK)     lo = m2;
        else if ((p & 0xFFFFu) >= (unsigned)TOPK) lo = m1;
      }
      if (lane == 0) s_T = lo;
    }
  } else {
    for (int r = 8; r < 16; ++r)
      full_round_l(zkey4, red, t, lane, wid, r, lo, w);
    if (t == 0) s_T = lo;
  }
  __syncthreads();
  const unsigned T = s_T;
  const float thresh = kinv(T);

#define COMPF(KF, OFS, OF) {                                                  \
      float v = 0.0f;                                                         \
      if (KF > T) {                                                           \
        v = kinv(KF) - thresh;                                                \
        const int p = atomicAdd(&s_nnz, 1);                                   \
        if (p < TOPK) { s_col[p] = base + OFS; s_val[p] = v; }                \
      }                                                                       \
      o.OF = v; }
#pragma unroll
  for (int j = 0; j < 12; ++j) {
    const uint4 k = zkey4[t + 256 * j];
    const int base = (t + 256 * j) * 4;
    float4 o;
    COMPF(k.x, 0, x)
    COMPF(k.y, 1, y)
    COMPF(k.z, 2, z)
    COMPF(k.w, 3, w)
    zv[t + 256 * j] = o;
  }
#undef COMPF
  __syncthreads();

  float a0 = 0.0f, a1 = 0.0f, a2 = 0.0f;
  if (use_wt) {
#pragma unroll 8
    for (int j = 0; j < TOPK; ++j) {
      const float v = s_val[j];
      const float* wp = WT + (size_t)s_col[j] * K_DIM;
      a0 += v * wp[t];
      a1 += v * wp[t + 256];
      a2 += v * wp[t + 512];
    }
  } else {
#pragma unroll 8
    for (int j = 0; j < TOPK; ++j) {
      const float v = s_val[j];
      const int col = s_col[j];
      a0 += v * DW[(size_t)(t)       * N_DIM + col];
      a1 += v * DW[(size_t)(t + 256) * N_DIM + col];
      a2 += v * DW[(size_t)(t + 512) * N_DIM + col];
    }
  }
  float* xr = XR + (size_t)row * K_DIM;
  xr[t]       = a0 + db[t];
  xr[t + 256] = a1 + db[t + 256];
  xr[t + 512] = a2 + db[t + 512];
}

// ---------------------------------------------------------------------------
extern "C" void kernel_launch(void* const* d_in, const int* in_sizes, int n_in,
                              void* d_out, int out_size, void* d_ws, size_t ws_size,
                              hipStream_t stream)
{
  (void)in_sizes; (void)n_in; (void)out_size;

  const float* x     = (const float*)d_in[0];
  const float* enc_w = (const float*)d_in[1];
  const float* enc_b = (const float*)d_in[2];
  const float* dec_w = (const float*)d_in[3];
  const float* dec_b = (const float*)d_in[4];
  // d_in[5] = k (constant 32, hardcoded as TOPK)

  float* out     = (float*)d_out;
  float* x_recon = out;                            // M*K floats
  float* z_sp    = out + (size_t)M_DIM * K_DIM;    // M*N floats

  const size_t WT_BYTES = (size_t)N_DIM * K_DIM * sizeof(float);      // 37.75 MB
  const size_t XPLANE   = (size_t)M_DIM * K_DIM * sizeof(unsigned short);
  const size_t WPLANE   = (size_t)N_DIM * K_DIM * sizeof(unsigned short);
  const size_t FULL     = WT_BYTES + 2 * XPLANE + 2 * WPLANE;         // 120 MiB
  const size_t CMAX_B   = (size_t)M_DIM * NCHUNK * sizeof(float);     // 6.3 MB
  const size_t FULL2    = FULL + CMAX_B;                              // 126 MiB

  char* ws = (char*)d_ws;
  const int use_wt   = (ws_size >= WT_BYTES) ? 1 : 0;
  const int use_mfma = (ws_size >= FULL) ? 1 : 0;
  const int use_cmax = (ws_size >= FULL2) ? 1 : 0;

  float*          WT   = (float*)ws;
  unsigned short* xhi  = (unsigned short*)(ws + WT_BYTES);
  unsigned short* xlo  = (unsigned short*)(ws + WT_BYTES + XPLANE);
  unsigned short* whi  = (unsigned short*)(ws + WT_BYTES + 2 * XPLANE);
  unsigned short* wlo  = (unsigned short*)(ws + WT_BYTES + 2 * XPLANE + WPLANE);
  float*          CMAX = (float*)(ws + FULL);

  if (use_wt || use_mfma)
    TopKSparseAutoencoder_51917564674099_prep<<<10752, 256, 0, stream>>>(
        x, enc_w, dec_w, xhi, xlo, whi, wlo, WT, use_wt, use_mfma);

  if (use_mfma) {
    dim3 tg(N_DIM / 128, M_DIM / 128);   // (96, 128)
    TopKSparseAutoencoder_51917564674099_kernel<<<tg, 256, 0, stream>>>(
        xhi, xlo, whi, wlo, enc_b, z_sp, CMAX, use_cmax);
  } else {
    dim3 tb(16, 16);
    dim3 tg(N_DIM / 128, M_DIM / 128);
    enc_gemm_f32_fb<<<tg, tb, 0, stream>>>(x, enc_w, enc_b, z_sp);
  }

  if (use_cmax)
    TopKSparseAutoencoder_51917564674099_zdecode<<<M_DIM / 4, 256, 0, stream>>>(
        z_sp, CMAX, WT, dec_b, x_recon);
  else
    topk_select_decode_fb<<<M_DIM, 256, 0, stream>>>(
        z_sp, WT, dec_w, dec_b, x_recon, use_wt);
}

// Round 6
// 2076.026 us; speedup vs baseline: 1.0835x; 1.0453x over previous
//
#include <hip/hip_runtime.h>

#define M_DIM 16384
#define K_DIM 768
#define N_DIM 12288
#define TOPK  32
#define NCHUNK (N_DIM / 128)   // 96 col-chunks per row

typedef float f32x4 __attribute__((ext_vector_type(4)));
typedef short s16x8 __attribute__((ext_vector_type(8)));

__device__ __forceinline__ unsigned f2u(float f) {
  union { float f; unsigned u; } v; v.f = f; return v.u;
}
__device__ __forceinline__ float u2f(unsigned u) {
  union { unsigned u; float f; } v; v.u = u; return v.f;
}
__device__ __forceinline__ unsigned fkey(float f) {
  const unsigned u = f2u(f);
  return u ^ (unsigned)(((int)u >> 31) | 0x80000000);
}
__device__ __forceinline__ float kinv(unsigned k) {
  return u2f((k & 0x80000000u) ? (k ^ 0x80000000u) : ~k);
}
__device__ __forceinline__ unsigned short bf16_rne(float f) {
  unsigned u = f2u(f);
  return (unsigned short)((u + 0x7FFFu + ((u >> 16) & 1u)) >> 16);
}

// ---------------------------------------------------------------------------
// Prep (fused): dec_w transpose + bf16 hi/lo splits of x and enc_w.
// ---------------------------------------------------------------------------
__global__ __launch_bounds__(256) void TopKSparseAutoencoder_51917564674099_prep(
    const float* __restrict__ x, const float* __restrict__ w,
    const float* __restrict__ dw,
    unsigned short* __restrict__ xhi, unsigned short* __restrict__ xlo,
    unsigned short* __restrict__ whi, unsigned short* __restrict__ wlo,
    float* __restrict__ WT, int do_t, int do_s)
{
  __shared__ float tile[32][33];
  const int b = (int)blockIdx.x;
  const int t = (int)threadIdx.x;

  if (b < 9216) {
    if (!do_t) return;
    const int bx = b % (N_DIM / 32);
    const int by = b / (N_DIM / 32);
    const int tx = t & 31, ty = t >> 5;           // 32 x 8
#pragma unroll
    for (int j = 0; j < 32; j += 8)
      tile[ty + j][tx] = dw[(size_t)(by * 32 + ty + j) * N_DIM + bx * 32 + tx];
    __syncthreads();
#pragma unroll
    for (int j = 0; j < 32; j += 8)
      WT[(size_t)(bx * 32 + ty + j) * K_DIM + by * 32 + tx] = tile[tx][ty + j];
    return;
  }
  if (!do_s) return;

  const float* src; unsigned short* dh; unsigned short* dl; int i, stride, n4;
  if (b < 9216 + 1024) {
    src = x; dh = xhi; dl = xlo;
    i = (b - 9216) * 256 + t; stride = 1024 * 256; n4 = M_DIM * K_DIM / 4;
  } else {
    src = w; dh = whi; dl = wlo;
    i = (b - 10240) * 256 + t; stride = 512 * 256; n4 = N_DIM * K_DIM / 4;
  }
  for (; i < n4; i += stride) {
    const float4 v = ((const float4*)src)[i];
    ushort4 h, l;
    h.x = bf16_rne(v.x); h.y = bf16_rne(v.y); h.z = bf16_rne(v.z); h.w = bf16_rne(v.w);
    l.x = bf16_rne(v.x - u2f((unsigned)h.x << 16));
    l.y = bf16_rne(v.y - u2f((unsigned)h.y << 16));
    l.z = bf16_rne(v.z - u2f((unsigned)h.z << 16));
    l.w = bf16_rne(v.w - u2f((unsigned)h.w << 16));
    ((ushort4*)dh)[i] = h;
    ((ushort4*)dl)[i] = l;
  }
}

// ---------------------------------------------------------------------------
// Main GEMM v2: 256x256 tile, BK=32, 8 waves (512 thr), bf16x3 MFMA.
// Counted-vmcnt deep pipeline (T3+T4): raw s_barrier + s_waitcnt vmcnt(8)
// keeps the next-next tile's global_load_lds in flight ACROSS barriers --
// the drain-to-0 at __syncthreads was the documented ~40% MfmaUtil ceiling.
// 2-deep prefetch, 2 LDS buffers (128KB), per-K-step:
//   compute(buf) ; barrier ; STAGE(buf, t+2) ; vmcnt(8) ; barrier
// Per-element accumulation order identical to v1 -> bitwise-identical Z.
// ---------------------------------------------------------------------------
__device__ __forceinline__ void mfma16(f32x4& d, s16x8 a, s16x8 b) {
  asm("v_mfma_f32_16x16x32_bf16 %0, %1, %2, %0" : "+v"(d) : "v"(a), "v"(b));
}

#define GL16(g, l) __builtin_amdgcn_global_load_lds(                      \
    (const __attribute__((address_space(1))) void*)(g),                   \
    (__attribute__((address_space(3))) void*)(l), 16, 0, 0)

__global__ __launch_bounds__(512, 1) void TopKSparseAutoencoder_51917564674099_kernel(
    const unsigned short* __restrict__ Ahi, const unsigned short* __restrict__ Alo,
    const unsigned short* __restrict__ Bhi, const unsigned short* __restrict__ Blo,
    const float* __restrict__ bias, float* __restrict__ Z,
    float* __restrict__ cmax, int do_cmax)
{
  __shared__ unsigned short lA[2][2][256][32];   // 64 KB  [buf][plane][row][k]
  __shared__ unsigned short lB[2][2][256][32];   // 64 KB
  __shared__ float cmx[256][2][2];               // 4 KB   [row][chunk][half]

  const int t    = (int)threadIdx.x;
  const int wid  = t >> 6;          // 0..7
  const int lane = t & 63;

  // XCD-aware bijective swizzle (nwg = 48*64 = 3072, divisible by 8)
  const int bid  = (int)(blockIdx.y * gridDim.x + blockIdx.x);
  const int bswz = (bid & 7) * (3072 / 8) + (bid >> 3);
  const int n0   = (bswz % 48) * 256;
  const int m0   = (bswz / 48) * 256;

  // staging: wave stages rows [32*wid, 32*wid+32) of A and B tiles, both
  // planes.  Lane i -> row (i>>2), 16B k-chunk (i&3); XOR swizzle applied
  // on the GLOBAL source k-chunk (LDS written linearly by global_load_lds).
  const int rr  = lane >> 2;
  const int kq  = lane & 3;
  const int rt0 = wid * 32 + rr;
  const int rt1 = rt0 + 16;
  const int kc0 = (kq ^ ((rt0 >> 1) & 3)) * 8;
  const int kc1 = (kq ^ ((rt1 >> 1) & 3)) * 8;
  const size_t offA0 = (size_t)(m0 + rt0) * K_DIM + kc0;
  const size_t offA1 = (size_t)(m0 + rt1) * K_DIM + kc1;
  const size_t offB0 = (size_t)(n0 + rt0) * K_DIM + kc0;
  const size_t offB1 = (size_t)(n0 + rt1) * K_DIM + kc1;

  const int wm = (wid >> 2) * 128;   // wave output: 128 rows x 64 cols
  const int wn = (wid & 3) * 64;
  const int lr = lane & 15;
  const int lc = lane >> 4;

  f32x4 acc[8][4];
#pragma unroll
  for (int i = 0; i < 8; ++i)
#pragma unroll
    for (int j = 0; j < 4; ++j) acc[i][j] = (f32x4){0.f, 0.f, 0.f, 0.f};

#define STG(B, KO) do {                                              \
    GL16(Ahi + offA0 + (KO), &lA[B][0][wid * 32][0]);                \
    GL16(Ahi + offA1 + (KO), &lA[B][0][wid * 32 + 16][0]);           \
    GL16(Alo + offA0 + (KO), &lA[B][1][wid * 32][0]);                \
    GL16(Alo + offA1 + (KO), &lA[B][1][wid * 32 + 16][0]);           \
    GL16(Bhi + offB0 + (KO), &lB[B][0][wid * 32][0]);                \
    GL16(Bhi + offB1 + (KO), &lB[B][0][wid * 32 + 16][0]);           \
    GL16(Blo + offB0 + (KO), &lB[B][1][wid * 32][0]);                \
    GL16(Blo + offB1 + (KO), &lB[B][1][wid * 32 + 16][0]);           \
  } while (0)

#define COMPUTE(B) do {                                              \
    s16x8 ah[8], al[8], bh[4], bl[4];                                \
    _Pragma("unroll")                                                \
    for (int i = 0; i < 8; ++i) {                                    \
      const int r = wm + i * 16 + lr;                                \
      const int p = (lc ^ ((r >> 1) & 3)) * 8;                       \
      ah[i] = *(const s16x8*)&lA[B][0][r][p];                        \
      al[i] = *(const s16x8*)&lA[B][1][r][p];                        \
    }                                                                \
    _Pragma("unroll")                                                \
    for (int j = 0; j < 4; ++j) {                                    \
      const int r = wn + j * 16 + lr;                                \
      const int p = (lc ^ ((r >> 1) & 3)) * 8;                       \
      bh[j] = *(const s16x8*)&lB[B][0][r][p];                        \
      bl[j] = *(const s16x8*)&lB[B][1][r][p];                        \
    }                                                                \
    __builtin_amdgcn_s_setprio(1);                                   \
    _Pragma("unroll")                                                \
    for (int i = 0; i < 8; ++i)                                      \
    _Pragma("unroll")                                                \
      for (int j = 0; j < 4; ++j) {                                  \
        mfma16(acc[i][j], ah[i], bh[j]);                             \
        mfma16(acc[i][j], ah[i], bl[j]);                             \
        mfma16(acc[i][j], al[i], bh[j]);                             \
      }                                                              \
    __builtin_amdgcn_s_setprio(0);                                   \
  } while (0)

  // prologue: tiles 0,1 in flight; wait tile0 (8 newest = tile1 stay out)
  STG(0, 0);
  STG(1, 32);
  asm volatile("s_waitcnt vmcnt(8)" ::: "memory");
  __builtin_amdgcn_s_barrier();
  __builtin_amdgcn_sched_barrier(0);

  // main loop: 24 K-steps total; steps 0..21 stage step+2
  for (int tt = 0; tt < 22; ++tt) {
    const int cb = tt & 1;
    COMPUTE(cb);
    __builtin_amdgcn_s_barrier();          // all waves done reading buf[cb]
    __builtin_amdgcn_sched_barrier(0);
    STG(cb, (tt + 2) * 32);                // prefetch tile tt+2 into buf[cb]
    asm volatile("s_waitcnt vmcnt(8)" ::: "memory");   // tile tt+1 landed
    __builtin_amdgcn_s_barrier();
    __builtin_amdgcn_sched_barrier(0);
  }
  COMPUTE(0);                              // tile 22
  asm volatile("s_waitcnt vmcnt(0)" ::: "memory");     // tile 23 landed
  __builtin_amdgcn_s_barrier();
  __builtin_amdgcn_sched_barrier(0);
  COMPUTE(1);                              // tile 23
#undef STG
#undef COMPUTE

  asm volatile("s_nop 7\n\ts_nop 7" :::);  // MFMA -> VALU read hazard guard

  // epilogue: C/D layout col = lane&15, row = (lane>>4)*4 + q
  float mx[8][4];
#pragma unroll
  for (int i = 0; i < 8; ++i)
#pragma unroll
    for (int q = 0; q < 4; ++q) mx[i][q] = -3.4e38f;

#pragma unroll
  for (int j = 0; j < 4; ++j) {
    const int col = n0 + wn + j * 16 + lr;
    const float bb = bias[col];
#pragma unroll
    for (int i = 0; i < 8; ++i) {
      const int r0 = m0 + wm + i * 16 + lc * 4;
#pragma unroll
      for (int q = 0; q < 4; ++q) {
        const float val = acc[i][j][q] + bb;
        Z[(size_t)(r0 + q) * N_DIM + col] = val;
        mx[i][q] = fmaxf(mx[i][q], val);
      }
    }
  }

  if (do_cmax) {
    // reduce over the 16 lanes sharing a row (lane bits 0..3)
#pragma unroll
    for (int s = 1; s < 16; s <<= 1)
#pragma unroll
      for (int i = 0; i < 8; ++i)
#pragma unroll
        for (int q = 0; q < 4; ++q)
          mx[i][q] = fmaxf(mx[i][q], __shfl_xor(mx[i][q], s));
    if (lr == 0) {
      const int c = wn >> 7;          // which 128-col chunk of this tile
      const int h = (wn >> 6) & 1;    // which 64-col half of the chunk
#pragma unroll
      for (int i = 0; i < 8; ++i)
#pragma unroll
        for (int q = 0; q < 4; ++q)
          cmx[wm + i * 16 + lc * 4 + q][c][h] = mx[i][q];
    }
    __syncthreads();
    if (t < 256) {
      const size_t rb = (size_t)(m0 + t) * NCHUNK + (n0 >> 7);
      cmax[rb]     = fmaxf(cmx[t][0][0], cmx[t][0][1]);
      cmax[rb + 1] = fmaxf(cmx[t][1][0], cmx[t][1][1]);
    }
  }
}

// ---------------------------------------------------------------------------
// fp32 VALU GEMM fallback (workspace too small for MFMA path)
// ---------------------------------------------------------------------------
__global__ void enc_gemm_f32_fb(
    const float* A, const float* B, const float* bias, float* Z)
{
  __shared__ float As[32][132];
  __shared__ float Bs[32][132];

  const int tx = (int)threadIdx.x;
  const int ty = (int)threadIdx.y;
  const int t  = ty * 16 + tx;
  const int n0 = (int)blockIdx.x * 128;
  const int m0 = (int)blockIdx.y * 128;
  const int r = t >> 1;
  const int h = (t & 1) * 16;

  float c[8][8];
#pragma unroll
  for (int i = 0; i < 8; ++i)
#pragma unroll
    for (int j = 0; j < 8; ++j) c[i][j] = 0.0f;

  for (int k0 = 0; k0 < K_DIM; k0 += 32) {
    const float* pa = A + (size_t)(m0 + r) * K_DIM + k0 + h;
    const float* pb = B + (size_t)(n0 + r) * K_DIM + k0 + h;
    float fa[16], fb[16];
#pragma unroll
    for (int j = 0; j < 16; ++j) fa[j] = pa[j];
#pragma unroll
    for (int j = 0; j < 16; ++j) fb[j] = pb[j];
#pragma unroll
    for (int j = 0; j < 16; ++j) As[h + j][r] = fa[j];
#pragma unroll
    for (int j = 0; j < 16; ++j) Bs[h + j][r] = fb[j];
    __syncthreads();

    for (int kk = 0; kk < 32; ++kk) {
      float av[8], bv[8];
#pragma unroll
      for (int i = 0; i < 8; ++i) av[i] = As[kk][ty * 8 + i];
#pragma unroll
      for (int j = 0; j < 8; ++j) bv[j] = Bs[kk][tx * 8 + j];
#pragma unroll
      for (int i = 0; i < 8; ++i)
#pragma unroll
        for (int j = 0; j < 8; ++j) c[i][j] += av[i] * bv[j];
    }
    __syncthreads();
  }

#pragma unroll
  for (int j = 0; j < 8; ++j) {
    const int col = n0 + tx * 8 + j;
    const float bb = bias[col];
#pragma unroll
    for (int i = 0; i < 8; ++i)
      Z[(size_t)(m0 + ty * 8 + i) * N_DIM + col] = c[i][j] + bb;
  }
}

// ---------------------------------------------------------------------------
// Fast decode v3 (UNCHANGED from R5): wave-autonomous, one row per wave.
// ---------------------------------------------------------------------------
__global__ __launch_bounds__(256, 4) void TopKSparseAutoencoder_51917564674099_zdecode(
    float* Z, const float* __restrict__ CMAX, const float* __restrict__ WT,
    const float* __restrict__ db, float* __restrict__ XR)
{
  __shared__ unsigned candk[4][256];
  __shared__ int      candi[4][256];
  __shared__ short    s_elig[4][NCHUNK];
  __shared__ int s_ne[4], s_cc[4], s_nnz[4];
  __shared__ int   s_col[4][TOPK];
  __shared__ float s_val[4][TOPK];

  const int t    = (int)threadIdx.x;
  const int lane = t & 63;
  const int wid  = t >> 6;
  const int row  = (int)blockIdx.x * 4 + wid;

  if (lane == 0) { s_ne[wid] = 0; s_cc[wid] = 0; s_nnz[wid] = 0; }
  if (lane < TOPK) { s_col[wid][lane] = 0; s_val[wid][lane] = 0.0f; }

  const f32x4* zr = (const f32x4*)(Z + (size_t)row * N_DIM);
  f32x4*       zw = (f32x4*)(Z + (size_t)row * N_DIM);

  const unsigned kA = fkey(CMAX[(size_t)row * NCHUNK + lane]);
  const unsigned kB = (lane < NCHUNK - 64) ? fkey(CMAX[(size_t)row * NCHUNK + 64 + lane]) : 0u;
  unsigned lo = 0;
  unsigned long long w = 1ULL << 32;
  for (int r = 0; r < 8; ++r) {
    w >>= 2;
    const unsigned wu = (unsigned)w;
    const unsigned m1 = lo + wu, m2 = lo + 2u * wu, m3 = lo + 3u * wu;
    unsigned p = (unsigned)((kA >= m1) + (kB >= m1)) |
                 ((unsigned)((kA >= m2) + (kB >= m2)) << 16);
    unsigned q = (unsigned)((kA >= m3) + (kB >= m3));
    p += __shfl_down(p, 32); q += __shfl_down(q, 32);
    p += __shfl_down(p, 16); q += __shfl_down(q, 16);
    p += __shfl_down(p, 8);  q += __shfl_down(q, 8);
    p += __shfl_down(p, 4);  q += __shfl_down(q, 4);
    p += __shfl_down(p, 2);  q += __shfl_down(q, 2);
    p += __shfl_down(p, 1);  q += __shfl_down(q, 1);
    p = __shfl(p, 0); q = __shfl(q, 0);
    if (q >= (unsigned)TOPK)                  lo = m3;
    else if ((p >> 16) >= (unsigned)TOPK)     lo = m2;
    else if ((p & 0xFFFFu) >= (unsigned)TOPK) lo = m1;
  }
  const unsigned B = lo;

  if (kA >= B) { const int p = atomicAdd(&s_ne[wid], 1); s_elig[wid][p] = (short)lane; }
  if (lane < NCHUNK - 64 && kB >= B) {
    const int p = atomicAdd(&s_ne[wid], 1); s_elig[wid][p] = (short)(lane + 64);
  }
  const int ne = s_ne[wid];

  for (int i = (lane >> 5); i < ne; i += 2) {
    const int c  = (int)s_elig[wid][i];
    const int f4 = (c << 5) + (lane & 31);
    const f32x4 v = zr[f4];
    const int base = f4 << 2;
    const unsigned k0 = fkey(v[0]), k1 = fkey(v[1]), k2 = fkey(v[2]), k3 = fkey(v[3]);
    if (k0 >= B) { int p = atomicAdd(&s_cc[wid], 1); if (p < 256) { candk[wid][p] = k0; candi[wid][p] = base; } }
    if (k1 >= B) { int p = atomicAdd(&s_cc[wid], 1); if (p < 256) { candk[wid][p] = k1; candi[wid][p] = base + 1; } }
    if (k2 >= B) { int p = atomicAdd(&s_cc[wid], 1); if (p < 256) { candk[wid][p] = k2; candi[wid][p] = base + 2; } }
    if (k3 >= B) { int p = atomicAdd(&s_cc[wid], 1); if (p < 256) { candk[wid][p] = k3; candi[wid][p] = base + 3; } }
  }
  const int cc = s_cc[wid];
  const f32x4 z4 = (f32x4){0.f, 0.f, 0.f, 0.f};

  if (cc <= 256) {
#pragma unroll 8
    for (int jj = 0; jj < 48; ++jj) zw[lane + 64 * jj] = z4;

    unsigned k[4];
#pragma unroll
    for (int i = 0; i < 4; ++i) k[i] = (lane + 64 * i < cc) ? candk[wid][lane + 64 * i] : 0u;
    lo = 0; w = 1ULL << 32;
    for (int r = 0; r < 16; ++r) {
      w >>= 2;
      const unsigned wu = (unsigned)w;
      const unsigned m1 = lo + wu, m2 = lo + 2u * wu, m3 = lo + 3u * wu;
      unsigned c1 = 0, c2 = 0, c3 = 0;
#pragma unroll
      for (int i = 0; i < 4; ++i) { c1 += (k[i] >= m1); c2 += (k[i] >= m2); c3 += (k[i] >= m3); }
      unsigned p = c1 | (c2 << 16), q = c3;
      p += __shfl_down(p, 32); q += __shfl_down(q, 32);
      p += __shfl_down(p, 16); q += __shfl_down(q, 16);
      p += __shfl_down(p, 8);  q += __shfl_down(q, 8);
      p += __shfl_down(p, 4);  q += __shfl_down(q, 4);
      p += __shfl_down(p, 2);  q += __shfl_down(q, 2);
      p += __shfl_down(p, 1);  q += __shfl_down(q, 1);
      p = __shfl(p, 0); q = __shfl(q, 0);
      if (q >= (unsigned)TOPK)                  lo = m3;
      else if ((p >> 16) >= (unsigned)TOPK)     lo = m2;
      else if ((p & 0xFFFFu) >= (unsigned)TOPK) lo = m1;
    }
    const unsigned T = lo;
    const float thresh = kinv(T);
    for (int i = lane; i < cc; i += 64) {
      const unsigned ck = candk[wid][i];
      if (ck > T) {
        const int p = atomicAdd(&s_nnz[wid], 1);
        if (p < TOPK) { s_col[wid][p] = candi[wid][i]; s_val[wid][p] = kinv(ck) - thresh; }
      }
    }
  } else {
    lo = 0; w = 1ULL << 32;
    for (int r = 0; r < 16; ++r) {
      w >>= 2;
      const unsigned wu = (unsigned)w;
      const unsigned m1 = lo + wu, m2 = lo + 2u * wu, m3 = lo + 3u * wu;
      unsigned c1 = 0, c2 = 0, c3 = 0;
      for (int j = 0; j < 48; ++j) {
        const f32x4 v = zr[lane + 64 * j];
        const unsigned k0 = fkey(v[0]), k1 = fkey(v[1]), k2 = fkey(v[2]), k3 = fkey(v[3]);
        c1 += (k0 >= m1) + (k1 >= m1) + (k2 >= m1) + (k3 >= m1);
        c2 += (k0 >= m2) + (k1 >= m2) + (k2 >= m2) + (k3 >= m2);
        c3 += (k0 >= m3) + (k1 >= m3) + (k2 >= m3) + (k3 >= m3);
      }
      unsigned p = c1 | (c2 << 16), q = c3;
      p += __shfl_down(p, 32); q += __shfl_down(q, 32);
      p += __shfl_down(p, 16); q += __shfl_down(q, 16);
      p += __shfl_down(p, 8);  q += __shfl_down(q, 8);
      p += __shfl_down(p, 4);  q += __shfl_down(q, 4);
      p += __shfl_down(p, 2);  q += __shfl_down(q, 2);
      p += __shfl_down(p, 1);  q += __shfl_down(q, 1);
      p = __shfl(p, 0); q = __shfl(q, 0);
      if (q >= (unsigned)TOPK)                  lo = m3;
      else if ((p >> 16) >= (unsigned)TOPK)     lo = m2;
      else if ((p & 0xFFFFu) >= (unsigned)TOPK) lo = m1;
    }
    const unsigned T = lo;
    const float thresh = kinv(T);
    for (int j = 0; j < 48; ++j) {
      const f32x4 v = zr[lane + 64 * j];
      const int base = (lane + 64 * j) * 4;
      const unsigned k0 = fkey(v[0]), k1 = fkey(v[1]), k2 = fkey(v[2]), k3 = fkey(v[3]);
      if (k0 > T) { int p = atomicAdd(&s_nnz[wid], 1); if (p < TOPK) { s_col[wid][p] = base;     s_val[wid][p] = kinv(k0) - thresh; } }
      if (k1 > T) { int p = atomicAdd(&s_nnz[wid], 1); if (p < TOPK) { s_col[wid][p] = base + 1; s_val[wid][p] = kinv(k1) - thresh; } }
      if (k2 > T) { int p = atomicAdd(&s_nnz[wid], 1); if (p < TOPK) { s_col[wid][p] = base + 2; s_val[wid][p] = kinv(k2) - thresh; } }
      if (k3 > T) { int p = atomicAdd(&s_nnz[wid], 1); if (p < TOPK) { s_col[wid][p] = base + 3; s_val[wid][p] = kinv(k3) - thresh; } }
      zw[lane + 64 * j] = z4;
    }
  }

  asm volatile("s_waitcnt vmcnt(0)" ::: "memory");
  const int nnz = (s_nnz[wid] < TOPK) ? s_nnz[wid] : TOPK;
  if (lane < nnz) Z[(size_t)row * N_DIM + s_col[wid][lane]] = s_val[wid][lane];

  const f32x4* WT4 = (const f32x4*)WT;
  f32x4 a0 = z4, a1 = z4, a2 = z4;
#pragma unroll 4
  for (int j = 0; j < TOPK; ++j) {
    const float v = s_val[wid][j];
    const size_t base = (size_t)s_col[wid][j] * (K_DIM / 4);
    const f32x4 w0 = WT4[base + lane];
    const f32x4 w1 = WT4[base + 64 + lane];
    const f32x4 w2 = WT4[base + 128 + lane];
    a0 += w0 * v;
    a1 += w1 * v;
    a2 += w2 * v;
  }
  const f32x4* db4 = (const f32x4*)db;
  f32x4* xr4 = (f32x4*)(XR + (size_t)row * K_DIM);
  xr4[lane]        = a0 + db4[lane];
  xr4[64 + lane]   = a1 + db4[64 + lane];
  xr4[128 + lane]  = a2 + db4[128 + lane];
}

// ---------------------------------------------------------------------------
// Decode fallback (no CMAX workspace): LDS-staged exact quad binsearch
// ---------------------------------------------------------------------------
__device__ __forceinline__ void full_round_l(
    const uint4* zk, unsigned red[][2][4], int t, int lane, int wid, int r,
    unsigned& lo, unsigned long long& w)
{
  w >>= 2;
  const unsigned wu = (unsigned)w;
  const unsigned m1 = lo + wu, m2 = lo + 2u * wu, m3 = lo + 3u * wu;
  unsigned c1 = 0, c2 = 0, c3 = 0;
#pragma unroll
  for (int j = 0; j < 12; ++j) {
    const uint4 k = zk[t + 256 * j];
    c1 += (k.x >= m1) + (k.y >= m1) + (k.z >= m1) + (k.w >= m1);
    c2 += (k.x >= m2) + (k.y >= m2) + (k.z >= m2) + (k.w >= m2);
    c3 += (k.x >= m3) + (k.y >= m3) + (k.z >= m3) + (k.w >= m3);
  }
  unsigned p = c1 | (c2 << 16), q = c3;
  p += __shfl_down(p, 32); q += __shfl_down(q, 32);
  p += __shfl_down(p, 16); q += __shfl_down(q, 16);
  p += __shfl_down(p, 8);  q += __shfl_down(q, 8);
  p += __shfl_down(p, 4);  q += __shfl_down(q, 4);
  p += __shfl_down(p, 2);  q += __shfl_down(q, 2);
  p += __shfl_down(p, 1);  q += __shfl_down(q, 1);
  const int par = r & 1;
  if (lane == 0) { red[par][0][wid] = p; red[par][1][wid] = q; }
  __syncthreads();
  const unsigned P = red[par][0][0] + red[par][0][1] + red[par][0][2] + red[par][0][3];
  const unsigned Q = red[par][1][0] + red[par][1][1] + red[par][1][2] + red[par][1][3];
  if (Q >= (unsigned)TOPK)                lo = m3;
  else if ((P >> 16) >= (unsigned)TOPK)   lo = m2;
  else if ((P & 0xFFFFu) >= (unsigned)TOPK) lo = m1;
}

__global__ __launch_bounds__(256, 3) void topk_select_decode_fb(
    float* Z, const float* __restrict__ WT, const float* __restrict__ DW,
    const float* __restrict__ db, float* __restrict__ XR, int use_wt)
{
  __shared__ uint4 zkey4[N_DIM / 4];
  __shared__ unsigned red[2][2][4];
  __shared__ unsigned cand[256];
  __shared__ unsigned s_T;
  __shared__ int s_cc;
  __shared__ int s_nnz;
  __shared__ int   s_col[TOPK];
  __shared__ float s_val[TOPK];

  const int row  = (int)blockIdx.x;
  const int t    = (int)threadIdx.x;
  const int lane = t & 63;
  const int wid  = t >> 6;

  float4* zv = (float4*)(Z + (size_t)row * N_DIM);

#pragma unroll
  for (int j = 0; j < 12; ++j) {
    const float4 v = zv[t + 256 * j];
    uint4 k;
    k.x = fkey(v.x); k.y = fkey(v.y); k.z = fkey(v.z); k.w = fkey(v.w);
    zkey4[t + 256 * j] = k;
  }
  if (t == 0) { s_nnz = 0; s_cc = 0; }
  if (t < TOPK) { s_col[t] = 0; s_val[t] = 0.0f; }
  __syncthreads();

  unsigned lo = 0;
  unsigned long long w = 1ULL << 32;
  for (int r = 0; r < 8; ++r)
    full_round_l(zkey4, red, t, lane, wid, r, lo, w);

#pragma unroll
  for (int j = 0; j < 12; ++j) {
    const uint4 k = zkey4[t + 256 * j];
    if (k.x >= lo) { int p = atomicAdd(&s_cc, 1); if (p < 256) cand[p] = k.x; }
    if (k.y >= lo) { int p = atomicAdd(&s_cc, 1); if (p < 256) cand[p] = k.y; }
    if (k.z >= lo) { int p = atomicAdd(&s_cc, 1); if (p < 256) cand[p] = k.z; }
    if (k.w >= lo) { int p = atomicAdd(&s_cc, 1); if (p < 256) cand[p] = k.w; }
  }
  __syncthreads();
  const int cc = s_cc;

  if (cc <= 256) {
    if (wid == 0) {
      const unsigned k0 = (lane       < cc) ? cand[lane]       : 0u;
      const unsigned k1 = (lane + 64  < cc) ? cand[lane + 64]  : 0u;
      const unsigned k2 = (lane + 128 < cc) ? cand[lane + 128] : 0u;
      const unsigned k3 = (lane + 192 < cc) ? cand[lane + 192] : 0u;
      for (int r = 8; r < 16; ++r) {
        w >>= 2;
        const unsigned wu = (unsigned)w;
        const unsigned m1 = lo + wu, m2 = lo + 2u * wu, m3 = lo + 3u * wu;
        unsigned c1 = (k0 >= m1) + (k1 >= m1) + (k2 >= m1) + (k3 >= m1);
        unsigned c2 = (k0 >= m2) + (k1 >= m2) + (k2 >= m2) + (k3 >= m2);
        unsigned c3 = (k0 >= m3) + (k1 >= m3) + (k2 >= m3) + (k3 >= m3);
        unsigned p = c1 | (c2 << 16), q = c3;
        p += __shfl_down(p, 32); q += __shfl_down(q, 32);
        p += __shfl_down(p, 16); q += __shfl_down(q, 16);
        p += __shfl_down(p, 8);  q += __shfl_down(q, 8);
        p += __shfl_down(p, 4);  q += __shfl_down(q, 4);
        p += __shfl_down(p, 2);  q += __shfl_down(q, 2);
        p += __shfl_down(p, 1);  q += __shfl_down(q, 1);
        p = __shfl(p, 0); q = __shfl(q, 0);
        if (q >= (unsigned)TOPK)                  lo = m3;
        else if ((p >> 16) >= (unsigned)TOPK)     lo = m2;
        else if ((p & 0xFFFFu) >= (unsigned)TOPK) lo = m1;
      }
      if (lane == 0) s_T = lo;
    }
  } else {
    for (int r = 8; r < 16; ++r)
      full_round_l(zkey4, red, t, lane, wid, r, lo, w);
    if (t == 0) s_T = lo;
  }
  __syncthreads();
  const unsigned T = s_T;
  const float thresh = kinv(T);

#define COMPF(KF, OFS, OF) {                                                  \
      float v = 0.0f;                                                         \
      if (KF > T) {                                                           \
        v = kinv(KF) - thresh;                                                \
        const int p = atomicAdd(&s_nnz, 1);                                   \
        if (p < TOPK) { s_col[p] = base + OFS; s_val[p] = v; }                \
      }                                                                       \
      o.OF = v; }
#pragma unroll
  for (int j = 0; j < 12; ++j) {
    const uint4 k = zkey4[t + 256 * j];
    const int base = (t + 256 * j) * 4;
    float4 o;
    COMPF(k.x, 0, x)
    COMPF(k.y, 1, y)
    COMPF(k.z, 2, z)
    COMPF(k.w, 3, w)
    zv[t + 256 * j] = o;
  }
#undef COMPF
  __syncthreads();

  float a0 = 0.0f, a1 = 0.0f, a2 = 0.0f;
  if (use_wt) {
#pragma unroll 8
    for (int j = 0; j < TOPK; ++j) {
      const float v = s_val[j];
      const float* wp = WT + (size_t)s_col[j] * K_DIM;
      a0 += v * wp[t];
      a1 += v * wp[t + 256];
      a2 += v * wp[t + 512];
    }
  } else {
#pragma unroll 8
    for (int j = 0; j < TOPK; ++j) {
      const float v = s_val[j];
      const int col = s_col[j];
      a0 += v * DW[(size_t)(t)       * N_DIM + col];
      a1 += v * DW[(size_t)(t + 256) * N_DIM + col];
      a2 += v * DW[(size_t)(t + 512) * N_DIM + col];
    }
  }
  float* xr = XR + (size_t)row * K_DIM;
  xr[t]       = a0 + db[t];
  xr[t + 256] = a1 + db[t + 256];
  xr[t + 512] = a2 + db[t + 512];
}

// ---------------------------------------------------------------------------
extern "C" void kernel_launch(void* const* d_in, const int* in_sizes, int n_in,
                              void* d_out, int out_size, void* d_ws, size_t ws_size,
                              hipStream_t stream)
{
  (void)in_sizes; (void)n_in; (void)out_size;

  const float* x     = (const float*)d_in[0];
  const float* enc_w = (const float*)d_in[1];
  const float* enc_b = (const float*)d_in[2];
  const float* dec_w = (const float*)d_in[3];
  const float* dec_b = (const float*)d_in[4];
  // d_in[5] = k (constant 32, hardcoded as TOPK)

  float* out     = (float*)d_out;
  float* x_recon = out;                            // M*K floats
  float* z_sp    = out + (size_t)M_DIM * K_DIM;    // M*N floats

  const size_t WT_BYTES = (size_t)N_DIM * K_DIM * sizeof(float);      // 37.75 MB
  const size_t XPLANE   = (size_t)M_DIM * K_DIM * sizeof(unsigned short);
  const size_t WPLANE   = (size_t)N_DIM * K_DIM * sizeof(unsigned short);
  const size_t FULL     = WT_BYTES + 2 * XPLANE + 2 * WPLANE;         // 120 MiB
  const size_t CMAX_B   = (size_t)M_DIM * NCHUNK * sizeof(float);     // 6.3 MB
  const size_t FULL2    = FULL + CMAX_B;                              // 126 MiB

  char* ws = (char*)d_ws;
  const int use_wt   = (ws_size >= WT_BYTES) ? 1 : 0;
  const int use_mfma = (ws_size >= FULL) ? 1 : 0;
  const int use_cmax = (ws_size >= FULL2) ? 1 : 0;

  float*          WT   = (float*)ws;
  unsigned short* xhi  = (unsigned short*)(ws + WT_BYTES);
  unsigned short* xlo  = (unsigned short*)(ws + WT_BYTES + XPLANE);
  unsigned short* whi  = (unsigned short*)(ws + WT_BYTES + 2 * XPLANE);
  unsigned short* wlo  = (unsigned short*)(ws + WT_BYTES + 2 * XPLANE + WPLANE);
  float*          CMAX = (float*)(ws + FULL);

  if (use_wt || use_mfma)
    TopKSparseAutoencoder_51917564674099_prep<<<10752, 256, 0, stream>>>(
        x, enc_w, dec_w, xhi, xlo, whi, wlo, WT, use_wt, use_mfma);

  if (use_mfma) {
    dim3 tg(N_DIM / 256, M_DIM / 256);   // (48, 64)
    TopKSparseAutoencoder_51917564674099_kernel<<<tg, 512, 0, stream>>>(
        xhi, xlo, whi, wlo, enc_b, z_sp, CMAX, use_cmax);
  } else {
    dim3 tb(16, 16);
    dim3 tg(N_DIM / 128, M_DIM / 128);
    enc_gemm_f32_fb<<<tg, tb, 0, stream>>>(x, enc_w, enc_b, z_sp);
  }

  if (use_cmax)
    TopKSparseAutoencoder_51917564674099_zdecode<<<M_DIM / 4, 256, 0, stream>>>(
        z_sp, CMAX, WT, dec_b, x_recon);
  else
    topk_select_decode_fb<<<M_DIM, 256, 0, stream>>>(
        z_sp, WT, dec_w, dec_b, x_recon, use_wt);
}